// Round 18
// baseline (2742.414 us; speedup 1.0000x reference)
//
#include <hip/hip_runtime.h>
#include <hip/hip_bf16.h>
#include <math.h>

#define B_   64
#define C_   1024
#define HW   100
#define MT_  20
#define P1   200
#define P2   120
#define BIGF 1.0e6f
#define EPSF 1e-8f
#define SQC  32.0f

// ---------------- workspace layout (float offsets) ----------------
static constexpr size_t F_J    = 0;
static constexpr size_t N_J    = (size_t)B_*P1*C_;        // 13,107,200
static constexpr size_t F_D    = F_J + N_J;
static constexpr size_t N_D    = (size_t)B_*P1*P1;        // 2,560,000
static constexpr size_t F_SQ   = F_D + N_D;
static constexpr size_t N_SQ   = (size_t)B_*P1;
static constexpr size_t F_KNN  = F_SQ + N_SQ;             // (unused now)
static constexpr size_t N_KNN  = (size_t)B_*P1*8;
static constexpr size_t F_MV   = F_KNN + N_KNN;
static constexpr size_t N_MV   = (size_t)B_*HW*HW;
static constexpr size_t F_MT   = F_MV + N_MV;
static constexpr size_t N_SM   = (size_t)B_*MT_*HW;
static constexpr size_t F_MFIX = F_MT + N_SM;
static constexpr size_t F_QKVF = F_MFIX + N_SM;
static constexpr size_t N_QKVF = (size_t)3*B_*HW*C_;
static constexpr size_t F_QKVT = F_QKVF + N_QKVF;
static constexpr size_t N_QKVT = (size_t)3*B_*MT_*C_;
static constexpr size_t F_FEAT = F_QKVT + N_QKVT;
static constexpr size_t N_FEAT = (size_t)B_*HW*C_;
static constexpr size_t N_SMC  = (size_t)B_*MT_*C_;
static constexpr size_t F_LANML= F_FEAT + N_FEAT;
static constexpr size_t F_T2   = F_LANML + N_SMC;
static constexpr size_t F_MI2TL= F_T2 + N_SMC;
static constexpr size_t F_S1   = F_MI2TL + N_SMC;
static constexpr size_t F_S2   = F_S1 + N_SM;
static constexpr size_t F_S4A  = F_S2 + N_SM;
static constexpr size_t F_S4B  = F_S4A + N_SM;
static constexpr size_t F_S5   = F_S4B + N_SM;
static constexpr size_t F_AV   = F_S5 + (size_t)B_*MT_*MT_;
static constexpr size_t F_BV   = F_AV + N_SM;
static constexpr size_t F_NL   = F_BV + N_SM;
static constexpr size_t F_AL   = F_NL + N_SMC;
static constexpr size_t F_BE   = F_AL + 64;
static constexpr size_t F_HS   = F_BE + 64;
static constexpr size_t F_HIST = F_HS + 8;
static constexpr size_t F_PA   = F_HIST + 1032;
static constexpr size_t F_PB   = F_PA + 6400;
// overlays: MlT2I = F_J [0..6,553,600) ; S3n = F_D [..128,000)
//           Pi2t = F_MV ; Pt2i = F_MV+128000 ; Ppre = F_MV+256000
//           W4Ml = F_T2 (T2b dead after tokproj)
// bf16 overlays (fl offsets; lifetimes audited disjoint):
//   XtV  = F_J          [0 .. 3,276,800)        [k_xt2 .. convqkv]
//   XtI  = +3,300,000   [.. 6,576,800)          [k_xt2 .. convqkv]
//   WVb  = +6,600,000   [.. 8,172,864)          [castw .. convqkv]
//   WIb  = +8,200,000   [.. 9,772,864)          [castw .. convqkv]
//   NVb  = +6,553,600   [.. 9,830,400)          [k_nv .. convout]
//   Wob16= +9,830,400   [.. 10,354,688)         [k_cast .. convout]
//   lanTb= +10,360,000  [.. 11,015,360)         [k_lanT .. textproj]
//   Wtb  = F_D          [.. F_D+2,097,152)      [k_cast .. textproj]
//   tout16 = F_D+1,000,000 ; ml2w16 = F_D+1,530,000  [post-textproj .. late gemms]
//     (S3n <= 128,000 fl -> disjoint from tout16/ml2w16)

typedef __attribute__((ext_vector_type(8))) short bfrag;
typedef __attribute__((ext_vector_type(4))) short bhalf;
typedef __attribute__((ext_vector_type(4))) float f32x4;
#define MFMA_B16(a,b,c) __builtin_amdgcn_mfma_f32_16x16x32_bf16(a,b,c,0,0,0)

__device__ inline short f2bf(float x){
  __hip_bfloat16 h = __float2bfloat16(x);
  return *reinterpret_cast<short*>(&h);
}

// ---------------- kernels ----------------

// LDS-tiled pack: J[b][p][c] = (p<HW ? vis : ir)[b][c][p(-HW)], both sides coalesced.
__global__ __launch_bounds__(256) void k_pack_j1(const float* __restrict__ vis,
    const float* __restrict__ ir, float* __restrict__ J){
  __shared__ float tile[32][33];
  int c0 = blockIdx.x*32, p0 = blockIdx.y*32, b = blockIdx.z;
  int j = threadIdx.x & 31, i0 = threadIdx.x >> 5;
  for (int i = i0; i < 32; i += 8){
    int p = p0 + j;
    float v = 0.f;
    if (p < P1) v = (p < HW) ? vis[((size_t)b*C_ + c0+i)*HW + p]
                             : ir [((size_t)b*C_ + c0+i)*HW + (p-HW)];
    tile[i][j] = v;
  }
  __syncthreads();
  for (int i = i0; i < 32; i += 8){
    int p = p0 + i;
    if (p < P1) J[((size_t)b*P1 + p)*C_ + c0 + j] = tile[j][i];
  }
}

__global__ void k_pack_j2(const float* __restrict__ feat, const float* __restrict__ lan,
                          float* __restrict__ J){
  int idx = blockIdx.x*256 + threadIdx.x;
  if (idx >= B_*P2*C_) return;
  int c = idx & (C_-1);
  int p = (idx >> 10) % P2;
  int b = idx / (C_*P2);
  float v;
  if (p < HW) v = feat[((size_t)b*HW + p)*C_ + c];
  else        v = lan [((size_t)b*C_ + c)*MT_ + (p-HW)];
  J[idx] = v;
}

__global__ void k_rowsq(const float* __restrict__ J, float* __restrict__ sq, int P){
  int row = blockIdx.x;
  const float* r = J + (size_t)row*C_;
  float s = 0.f;
  for (int c = threadIdx.x; c < C_; c += 64){ float v = r[c]; s += v*v; }
  for (int o = 32; o > 0; o >>= 1) s += __shfl_down(s, o);
  if (threadIdx.x == 0) sq[row] = s;
}

// 64x64 tile, 4x4 acc, TRANSPOSED LDS [kk][row] (pad 68 => 16B-aligned b128
// reads; conflict-free read path). Same per-element kk order as original =>
// bit-identical distances (kNN-safe).
__global__ __launch_bounds__(256) void k_gram_dist(const float* __restrict__ J,
    const float* __restrict__ sq, float* __restrict__ D, int P){
  __shared__ __align__(16) float Xi[32][68];
  __shared__ __align__(16) float Xj[32][68];
  int b = blockIdx.z;
  int r0 = blockIdx.x*64, s0 = blockIdx.y*64;
  int tx = threadIdx.x & 15, ty = threadIdx.x >> 4;
  const float* Jb = J + (size_t)b*P*C_;
  float acc[4][4];
  #pragma unroll
  for (int u = 0; u < 4; u++)
    #pragma unroll
    for (int v = 0; v < 4; v++) acc[u][v] = 0.f;
  for (int c0 = 0; c0 < C_; c0 += 32){
    for (int e = threadIdx.x; e < 2048; e += 256){
      int rr = e >> 5, cc = e & 31;
      Xi[cc][rr] = (r0+rr < P) ? Jb[(size_t)(r0+rr)*C_ + c0+cc] : 0.f;
      Xj[cc][rr] = (s0+rr < P) ? Jb[(size_t)(s0+rr)*C_ + c0+cc] : 0.f;
    }
    __syncthreads();
    for (int kk = 0; kk < 32; kk++){
      float4 xr4 = *(const float4*)&Xi[kk][ty*4];
      float4 xs4 = *(const float4*)&Xj[kk][tx*4];
      float xr[4] = {xr4.x, xr4.y, xr4.z, xr4.w};
      float xs[4] = {xs4.x, xs4.y, xs4.z, xs4.w};
      #pragma unroll
      for (int u = 0; u < 4; u++)
        #pragma unroll
        for (int v = 0; v < 4; v++) acc[u][v] += xr[u]*xs[v];
    }
    __syncthreads();
  }
  #pragma unroll
  for (int u = 0; u < 4; u++){
    #pragma unroll
    for (int v = 0; v < 4; v++){
      int r = r0 + ty*4 + u, s = s0 + tx*4 + v;
      if (r < P && s < P){
        float d2 = sq[b*P+r] + sq[b*P+s] - 2.f*acc[u][v];
        D[((size_t)b*P + r)*P + s] = sqrtf(fmaxf(d2, 0.f));
      }
    }
  }
}

// Fused kNN + buildw + register-FW + minmax(window) -> normalized output.
// kNN: one thread per row, ascending scan, strictly-less => smallest index on
// ties (same semantics as the old wave-reduce kernel). Also block 0 zeroes the
// median histogram and seeds hs (removes memset/init launches).
template<int P, int NT, int RP, int CP, int R0, int C0, int RR, int CC>
__global__ __launch_bounds__(1024) void k_fwx(const float* __restrict__ D,
    float* __restrict__ outM, float* __restrict__ hs, unsigned* __restrict__ hist){
  constexpr int PR = P/RP;
  constexpr int PC = P/CP;
  constexpr int NTH = PR*PC;
  __shared__ float rowk[P], colk[P];
  __shared__ int kl[P*8];
  __shared__ float rmn[1024], rmx[1024];
  int b = blockIdx.x;
  const float* Db = D + (size_t)b*P*P;
  int tid = threadIdx.x;
  if (b == 0){
    for (int e = tid; e < 1025; e += NT) hist[e] = 0u;
    if (tid == 0){ hs[0] = 0.f; hs[1] = 1.0f; }
  }
  // ---- in-kernel kNN (rows 0..P-1, one thread each) ----
  if (tid < P){
    int chosen[8];
    const float* Dr = Db + (size_t)tid*P;
    for (int k = 0; k < 8; k++){
      float bv = 3.4e38f; int bj = 1 << 30;
      for (int j = 0; j < P; j++){
        float d = Dr[j];
        if (j == tid) d += BIGF;
        bool sk = false;
        #pragma unroll
        for (int c = 0; c < 8; c++) if (c < k) sk = sk || (chosen[c] == j);
        if (!sk && d < bv){ bv = d; bj = j; }
      }
      chosen[k] = bj;
      kl[tid*8 + k] = bj;
    }
  }
  __syncthreads();
  bool act = tid < NTH;
  int pi = tid / PC, pj = tid - pi*PC;
  int i0 = pi*RP, j0 = pj*CP;
  float w[RP][CP];
  if (act){
    #pragma unroll
    for (int r = 0; r < RP; r++){
      float4 v = *(const float4*)(Db + (size_t)(i0+r)*P + j0);
      w[r][0]=v.x; w[r][1]=v.y; w[r][2]=v.z; w[r][3]=v.w;
      int i = i0 + r;
      #pragma unroll
      for (int c = 0; c < CP; c++){
        int j = j0 + c;
        if (i == j) w[r][c] = 0.f;
        else {
          const int* ki = &kl[i*8];
          const int* kj = &kl[j*8];
          bool e = false;
          #pragma unroll
          for (int k = 0; k < 8; k++) e = e || (ki[k] == j) || (kj[k] == i);
          if (!e) w[r][c] = BIGF;
        }
      }
    }
  }
  __syncthreads();
  for (int k = 0; k < P; k++){
    if (act){
      #pragma unroll
      for (int r = 0; r < RP; r++){
        if (i0 + r == k)
          *(float4*)(rowk + j0) = make_float4(w[r][0],w[r][1],w[r][2],w[r][3]);
      }
      #pragma unroll
      for (int c = 0; c < CP; c++){
        if (j0 + c == k){
          #pragma unroll
          for (int r = 0; r < RP; r++) colk[i0+r] = w[r][c];
        }
      }
    }
    __syncthreads();
    if (act){
      float4 rk4 = *(const float4*)(rowk + j0);
      float rk[4] = {rk4.x, rk4.y, rk4.z, rk4.w};
      float ck[RP];
      #pragma unroll
      for (int r = 0; r < RP; r++) ck[r] = colk[i0+r];
      #pragma unroll
      for (int r = 0; r < RP; r++)
        #pragma unroll
        for (int c = 0; c < CP; c++)
          w[r][c] = fminf(w[r][c], ck[r] + rk[c]);
    }
    __syncthreads();
  }
  // window min/max + normalize + write
  float mn = 3.4e38f, mx = -3.4e38f;
  if (act){
    #pragma unroll
    for (int r = 0; r < RP; r++){
      int i = i0 + r;
      if (i >= R0 && i < R0+RR){
        #pragma unroll
        for (int c = 0; c < CP; c++){
          int j = j0 + c;
          if (j >= C0 && j < C0+CC){
            mn = fminf(mn, w[r][c]); mx = fmaxf(mx, w[r][c]);
          }
        }
      }
    }
  }
  rmn[tid] = mn; rmx[tid] = mx;
  __syncthreads();
  for (int o = 512; o > 0; o >>= 1){
    if (tid < o && tid + o < NT){
      rmn[tid] = fminf(rmn[tid], rmn[tid+o]);
      rmx[tid] = fmaxf(rmx[tid], rmx[tid+o]);
    }
    __syncthreads();
  }
  mn = rmn[0]; mx = rmx[0];
  float inv = 1.f/(mx - mn + EPSF);
  if (act){
    #pragma unroll
    for (int r = 0; r < RP; r++){
      int i = i0 + r;
      if (i >= R0 && i < R0+RR){
        #pragma unroll
        for (int c = 0; c < CP; c++){
          int j = j0 + c;
          if (j >= C0 && j < C0+CC)
            outM[((size_t)b*RR + (i-R0))*CC + (j-C0)] = (w[r][c] - mn)*inv;
        }
      }
    }
  }
}

__global__ __launch_bounds__(256) void k_med_hist(const float* __restrict__ x, int N,
                           const float* __restrict__ hs, unsigned* __restrict__ hist){
  __shared__ unsigned lh[1025];
  for (int i = threadIdx.x; i < 1025; i += 256) lh[i] = 0u;
  __syncthreads();
  float lo = hs[0], hi = hs[1];
  float scale = 1024.f/(hi - lo);
  unsigned below = 0;
  int idx = blockIdx.x*256 + threadIdx.x;
  int stride = gridDim.x*256;
  for (int i = idx; i < N; i += stride){
    float v = x[i];
    if (v < lo) below++;
    else if (v < hi){
      int bn = (int)((v - lo)*scale);
      if (bn > 1023) bn = 1023;
      atomicAdd(&lh[bn], 1u);
    }
  }
  for (int o = 32; o > 0; o >>= 1) below += __shfl_down(below, o);
  if ((threadIdx.x & 63) == 0 && below) atomicAdd(&lh[1024], below);
  __syncthreads();
  for (int i = threadIdx.x; i < 1025; i += 256){
    unsigned v = lh[i];
    if (v) atomicAdd(&hist[i], v);
  }
}

// select + zero hist for next use (removes memset launches)
__global__ void k_med_select(float* hs, unsigned* __restrict__ hist, int k){
  if (threadIdx.x == 0){
    float lo = hs[0], hi = hs[1], w = (hi - lo)*(1.f/1024.f);
    unsigned cum = hist[1024];
    int bf = 1023;
    for (int bn = 0; bn < 1024; bn++){
      unsigned h = hist[bn];
      if (cum + h > (unsigned)k){ bf = bn; break; }
      cum += h;
    }
    hs[0] = lo + bf*w; hs[1] = lo + (bf+1)*w;
  }
  __syncthreads();
  for (int i = threadIdx.x; i < 1025; i += 64) hist[i] = 0u;
}

__global__ __launch_bounds__(256) void k_mgap(const float* __restrict__ Mv,
    const float* __restrict__ W1, const float* __restrict__ b1,
    const float* __restrict__ sc, const float* __restrict__ hs,
    float* __restrict__ alpha, float* __restrict__ bet){
  __shared__ float sr[256];
  int b = blockIdx.x;
  float lam1s = 1.f/(1.f + expf(-sc[0]));
  float sig = 0.5f*(hs[0] + hs[1]);
  float inv2s = 1.f/(2.f*sig*sig);
  const float* Mb = Mv + (size_t)b*HW*HW;
  float s = 0.f;
  for (int e = threadIdx.x; e < HW*HW; e += 256){
    float v = Mb[e];
    float f = expf(-v*v*inv2s);
    s += lam1s*f + (1.f - lam1s)*(W1[e]*f + b1[e]);
  }
  sr[threadIdx.x] = s; __syncthreads();
  for (int o = 128; o > 0; o >>= 1){
    if ((int)threadIdx.x < o) sr[threadIdx.x] += sr[threadIdx.x+o];
    __syncthreads();
  }
  if (threadIdx.x == 0){
    float mg = sr[0]*(1.f/(HW*HW));
    alpha[b] = 1.f/(1.f + expf(-(sc[8]*mg + sc[9])));
    bet[b]   = 1.f/(1.f + expf(-(sc[10]*mg + sc[11])));
  }
}

// cast f32 weights -> bf16 (both modality weight tensors, 3x1024x1024 each)
__global__ void k_castw(const float* __restrict__ a, const float* __restrict__ b,
                        short* __restrict__ oa, short* __restrict__ ob){
  int i = (blockIdx.x*256 + threadIdx.x)*4;
  if (i >= 3*C_*C_) return;
  float4 va = *(const float4*)(a + i);
  float4 vb = *(const float4*)(b + i);
  short ra[4] = { f2bf(va.x), f2bf(va.y), f2bf(va.z), f2bf(va.w) };
  short rb[4] = { f2bf(vb.x), f2bf(vb.y), f2bf(vb.z), f2bf(vb.w) };
  *(bhalf*)(oa + i) = *(bhalf*)ra;
  *(bhalf*)(ob + i) = *(bhalf*)rb;
}

// cast n floats -> bf16 (n multiple of 4)
__global__ void k_cast(const float* __restrict__ a, short* __restrict__ oa, int n){
  int i = (blockIdx.x*256 + threadIdx.x)*4;
  if (i >= n) return;
  float4 va = *(const float4*)(a + i);
  short ra[4] = { f2bf(va.x), f2bf(va.y), f2bf(va.z), f2bf(va.w) };
  *(bhalf*)(oa + i) = *(bhalf*)ra;
}

// cast two tensors in one launch
__global__ void k_cast2(const float* __restrict__ a, const float* __restrict__ b,
                        short* __restrict__ oa, short* __restrict__ ob,
                        int n1, int n2){
  int i = (blockIdx.x*256 + threadIdx.x)*4;
  if (i < n1){
    float4 va = *(const float4*)(a + i);
    short ra[4] = { f2bf(va.x), f2bf(va.y), f2bf(va.z), f2bf(va.w) };
    *(bhalf*)(oa + i) = *(bhalf*)ra;
  } else if (i < n1 + n2){
    int k = i - n1;
    float4 vb = *(const float4*)(b + k);
    short rb[4] = { f2bf(vb.x), f2bf(vb.y), f2bf(vb.z), f2bf(vb.w) };
    *(bhalf*)(ob + k) = *(bhalf*)rb;
  }
}

// fused transpose [b][c][t] -> [b][t][c] bf16 for vis & ir, + feat (f32) output
__global__ __launch_bounds__(256) void k_xt2(const float* __restrict__ V,
    const float* __restrict__ I, const float* __restrict__ alpha,
    const float* __restrict__ bet, short* __restrict__ XtV,
    short* __restrict__ XtI, float* __restrict__ feat){
  __shared__ float tv[32][33], ti[32][33];
  int c0 = blockIdx.x*32, t0 = blockIdx.y*32, b = blockIdx.z;
  int j = threadIdx.x & 31, i0 = threadIdx.x >> 5;
  for (int i = i0; i < 32; i += 8){
    int t = t0 + j;
    float a = 0.f, c = 0.f;
    if (t < HW){
      a = V[((size_t)b*C_ + c0+i)*HW + t];
      c = I[((size_t)b*C_ + c0+i)*HW + t];
    }
    tv[i][j] = a; ti[i][j] = c;
  }
  __syncthreads();
  float al = alpha[b], bt = bet[b];
  for (int i = i0; i < 32; i += 8){
    int t = t0 + i;
    if (t < HW){
      float fv = tv[j][i], fi = ti[j][i];
      size_t off = ((size_t)b*HW + t)*C_ + c0 + j;
      XtV[off] = f2bf(fv);
      XtI[off] = f2bf(fi);
      feat[off] = al*fv + bt*fi;
    }
  }
}

// transpose lan [b][c][20] f32 -> lanT [(b*20+t)][c] bf16
__global__ __launch_bounds__(256) void k_lanT(const float* __restrict__ lan,
                                              short* __restrict__ lanT){
  __shared__ float tile[32][21];
  int c0 = blockIdx.x*32, b = blockIdx.y;
  for (int e = threadIdx.x; e < 32*MT_; e += 256){
    int c = e / MT_, t = e - c*MT_;
    tile[c][t] = lan[((size_t)b*C_ + c0+c)*MT_ + t];
  }
  __syncthreads();
  for (int e = threadIdx.x; e < 32*MT_; e += 256){
    int t = e >> 5, c = e & 31;
    lanT[((size_t)(b*MT_ + t))*C_ + c0 + c] = f2bf(tile[c][t]);
  }
}

// Direct global->register MFMA conv1x1 + IN + ReLU + alpha/beta combine.
// m-tile 128 (round-10 config, measured best 425us, FROZEN).
__global__ __launch_bounds__(256) void k_convqkv_mfma(
    const short* __restrict__ XtV, const short* __restrict__ XtI,
    const short* __restrict__ WV,  const short* __restrict__ WI,
    const float* __restrict__ vg, const float* __restrict__ vbe,
    const float* __restrict__ ig, const float* __restrict__ ibe,
    const float* __restrict__ alpha, const float* __restrict__ bet,
    float* __restrict__ out){
  int m0 = blockIdx.x*128;
  int wsel = blockIdx.y;
  int b = blockIdx.z;
  int tid = threadIdx.x;
  int lane = tid & 63, w = tid >> 6;
  int lg = lane >> 4, lr = lane & 15;
  f32x4 acc[7][2][2];
  #pragma unroll
  for (int tf = 0; tf < 7; tf++)
    #pragma unroll
    for (int mf = 0; mf < 2; mf++)
      #pragma unroll
      for (int md = 0; md < 2; md++)
        acc[tf][mf][md] = (f32x4){0.f,0.f,0.f,0.f};
  const short* xvp = XtV + (size_t)b*HW*C_ + (size_t)lr*C_ + lg*8;
  const short* xip = XtI + (size_t)b*HW*C_ + (size_t)lr*C_ + lg*8;
  const short* wvp = WV + (size_t)wsel*C_*C_ + (size_t)(m0 + w*32 + lr)*C_ + lg*8;
  const short* wip = WI + (size_t)wsel*C_*C_ + (size_t)(m0 + w*32 + lr)*C_ + lg*8;
  const bfrag zf = {0,0,0,0,0,0,0,0};
  for (int k0 = 0; k0 < C_; k0 += 32){
    bfrag bw0v = *(const bfrag*)(wvp + k0);
    bfrag bw1v = *(const bfrag*)(wvp + (size_t)16*C_ + k0);
    bfrag bw0i = *(const bfrag*)(wip + k0);
    bfrag bw1i = *(const bfrag*)(wip + (size_t)16*C_ + k0);
    #pragma unroll
    for (int tf = 0; tf < 7; tf++){
      bfrag axv = zf, axi = zf;
      if (tf*16 + lr < HW){
        axv = *(const bfrag*)(xvp + (size_t)tf*16*C_ + k0);
        axi = *(const bfrag*)(xip + (size_t)tf*16*C_ + k0);
      }
      acc[tf][0][0] = MFMA_B16(axv, bw0v, acc[tf][0][0]);
      acc[tf][1][0] = MFMA_B16(axv, bw1v, acc[tf][1][0]);
      acc[tf][0][1] = MFMA_B16(axi, bw0i, acc[tf][0][1]);
      acc[tf][1][1] = MFMA_B16(axi, bw1i, acc[tf][1][1]);
    }
  }
  float al = alpha[b], bt = bet[b];
  float* ob = out + ((size_t)(wsel*B_ + b))*HW*C_;
  #pragma unroll
  for (int mf = 0; mf < 2; mf++){
    int m = m0 + w*32 + mf*16 + lr;
    float s1v=0.f,s2v=0.f,s1i=0.f,s2i=0.f;
    #pragma unroll
    for (int tf = 0; tf < 7; tf++){
      #pragma unroll
      for (int r = 0; r < 4; r++){
        int t = tf*16 + lg*4 + r;
        if (t < HW){
          float yv = acc[tf][mf][0][r], yi = acc[tf][mf][1][r];
          s1v += yv; s2v += yv*yv; s1i += yi; s2i += yi*yi;
        }
      }
    }
    s1v += __shfl_xor(s1v,16); s1v += __shfl_xor(s1v,32);
    s2v += __shfl_xor(s2v,16); s2v += __shfl_xor(s2v,32);
    s1i += __shfl_xor(s1i,16); s1i += __shfl_xor(s1i,32);
    s2i += __shfl_xor(s2i,16); s2i += __shfl_xor(s2i,32);
    float muv = s1v*0.01f, varv = s2v*0.01f - muv*muv;
    float mui = s1i*0.01f, vari = s2i*0.01f - mui*mui;
    float scv = vg[wsel*C_+m]/sqrtf(varv+1e-5f);
    float shv = vbe[wsel*C_+m] - muv*scv;
    float sci = ig[wsel*C_+m]/sqrtf(vari+1e-5f);
    float shi = ibe[wsel*C_+m] - mui*sci;
    #pragma unroll
    for (int tf = 0; tf < 7; tf++){
      #pragma unroll
      for (int r = 0; r < 4; r++){
        int t = tf*16 + lg*4 + r;
        if (t < HW){
          float yv = fmaxf(acc[tf][mf][0][r]*scv + shv, 0.f);
          float yi = fmaxf(acc[tf][mf][1][r]*sci + shi, 0.f);
          ob[(size_t)t*C_ + m] = al*yv + bt*yi;
        }
      }
    }
  }
}

// Packed-row GEMM: out[row][n] = sum_c X[row][c]*W16[n][c] + bias[n], 1280 rows.
__global__ __launch_bounds__(256) void k_tokproj_mfma(
    const float* __restrict__ X, const short* __restrict__ W16,
    const float* __restrict__ bias, float* __restrict__ out){
  constexpr int NROW = B_*MT_;
  int n0 = blockIdx.x*128;
  int t0 = blockIdx.y*112;
  int tid = threadIdx.x;
  int lane = tid & 63, w = tid >> 6;
  int lg = lane >> 4, lr = lane & 15;
  f32x4 acc[7][2];
  #pragma unroll
  for (int tf = 0; tf < 7; tf++)
    #pragma unroll
    for (int mf = 0; mf < 2; mf++)
      acc[tf][mf] = (f32x4){0.f,0.f,0.f,0.f};
  const short* wp = W16 + (size_t)(n0 + w*32 + lr)*C_ + lg*8;
  const bfrag zf = {0,0,0,0,0,0,0,0};
  for (int k0 = 0; k0 < C_; k0 += 32){
    bfrag bw0 = *(const bfrag*)(wp + k0);
    bfrag bw1 = *(const bfrag*)(wp + (size_t)16*C_ + k0);
    #pragma unroll
    for (int tf = 0; tf < 7; tf++){
      bfrag ax = zf;
      int row = t0 + tf*16 + lr;
      if (row < NROW){
        const float* ap = X + (size_t)row*C_ + k0 + lg*8;
        float4 u = *(const float4*)ap;
        float4 v = *(const float4*)(ap + 4);
        ax[0]=f2bf(u.x); ax[1]=f2bf(u.y); ax[2]=f2bf(u.z); ax[3]=f2bf(u.w);
        ax[4]=f2bf(v.x); ax[5]=f2bf(v.y); ax[6]=f2bf(v.z); ax[7]=f2bf(v.w);
      }
      acc[tf][0] = MFMA_B16(ax, bw0, acc[tf][0]);
      acc[tf][1] = MFMA_B16(ax, bw1, acc[tf][1]);
    }
  }
  #pragma unroll
  for (int mf = 0; mf < 2; mf++){
    int n = n0 + w*32 + mf*16 + lr;
    float bv = bias[n];
    #pragma unroll
    for (int tf = 0; tf < 7; tf++){
      #pragma unroll
      for (int r = 0; r < 4; r++){
        int row = t0 + tf*16 + lg*4 + r;
        if (row < NROW) out[(size_t)row*C_ + n] = acc[tf][mf][r] + bv;
      }
    }
  }
}

#define TPAD 36
// MFMA final conv: out[b][n][t] = sum_m W[n][m]*NVb[b][t][m] + bias[n]
__global__ __launch_bounds__(256) void k_convout_mfma(
    const short* __restrict__ NVb, const short* __restrict__ Wb,
    const float* __restrict__ bias, float* __restrict__ out){
  __shared__ short xs[112*TPAD];
  __shared__ short wsm[128*TPAD];
  int n0 = blockIdx.x*128, b = blockIdx.y;
  int tid = threadIdx.x;
  int lane = tid & 63, w = tid >> 6;
  int lg = lane >> 4, lr = lane & 15;
  for (int e = tid; e < 12*TPAD; e += 256) xs[100*TPAD + e] = 0;
  f32x4 acc[7][2];
  #pragma unroll
  for (int tf = 0; tf < 7; tf++)
    #pragma unroll
    for (int nf = 0; nf < 2; nf++)
      acc[tf][nf] = (f32x4){0.f,0.f,0.f,0.f};
  const short* xg = NVb + (size_t)b*HW*C_;
  const short* wg = Wb + (size_t)n0*C_;
  int rr0 = tid >> 3, kk = (tid & 7)*4;
  for (int k0 = 0; k0 < C_; k0 += 32){
    __syncthreads();
    for (int rr = rr0; rr < HW; rr += 32)
      *(uint2*)&xs[rr*TPAD + kk] = *(const uint2*)(xg + (size_t)rr*C_ + k0 + kk);
    for (int rr = rr0; rr < 128; rr += 32)
      *(uint2*)&wsm[rr*TPAD + kk] = *(const uint2*)(wg + (size_t)rr*C_ + k0 + kk);
    __syncthreads();
    const short* pw0 = &wsm[(w*32 + lr)*TPAD + lg*4];
    const short* pw1 = &wsm[(w*32 + 16 + lr)*TPAD + lg*4];
    bhalf l0, h0;
    l0 = *(const bhalf*)pw0; h0 = *(const bhalf*)(pw0 + 16);
    bfrag aw0 = {l0[0],l0[1],l0[2],l0[3],h0[0],h0[1],h0[2],h0[3]};
    l0 = *(const bhalf*)pw1; h0 = *(const bhalf*)(pw1 + 16);
    bfrag aw1 = {l0[0],l0[1],l0[2],l0[3],h0[0],h0[1],h0[2],h0[3]};
    #pragma unroll
    for (int tf = 0; tf < 7; tf++){
      const short* pb = &xs[(tf*16 + lr)*TPAD + lg*4];
      bhalf bl_ = *(const bhalf*)pb, bh_ = *(const bhalf*)(pb + 16);
      bfrag bx = {bl_[0],bl_[1],bl_[2],bl_[3],bh_[0],bh_[1],bh_[2],bh_[3]};
      acc[tf][0] = MFMA_B16(aw0, bx, acc[tf][0]);
      acc[tf][1] = MFMA_B16(aw1, bx, acc[tf][1]);
    }
  }
  float* ob = out + (size_t)b*C_*HW;
  #pragma unroll
  for (int nf = 0; nf < 2; nf++){
    #pragma unroll
    for (int r = 0; r < 4; r++){
      int n = n0 + w*32 + nf*16 + lg*4 + r;
      float bv = bias[n];
      #pragma unroll
      for (int tf = 0; tf < 7; tf++){
        int t = tf*16 + lr;
        if (t < HW) ob[(size_t)n*HW + t] = acc[tf][nf][r] + bv;
      }
    }
  }
}

// MFMA text projections over packed token rows (row = b*20+t, 1280 rows).
__global__ __launch_bounds__(256) void k_textproj_mfma(
    const short* __restrict__ lanT, const short* __restrict__ Wt,
    const float* __restrict__ tb, float* __restrict__ QKVt, float* __restrict__ lanML){
  constexpr int NROW = B_*MT_;
  __shared__ short xs[112*TPAD];
  __shared__ short wsm[128*TPAD];
  int m0 = blockIdx.x*128;
  int t0 = blockIdx.y*112;
  int wsel = blockIdx.z;
  int tid = threadIdx.x;
  int lane = tid & 63, w = tid >> 6;
  int lg = lane >> 4, lr = lane & 15;
  f32x4 acc[7][2];
  #pragma unroll
  for (int tf = 0; tf < 7; tf++)
    #pragma unroll
    for (int mf = 0; mf < 2; mf++)
      acc[tf][mf] = (f32x4){0.f,0.f,0.f,0.f};
  const short* wg = Wt + (size_t)wsel*C_*C_ + (size_t)m0*C_;
  int rr0 = tid >> 3, kk = (tid & 7)*4;
  for (int k0 = 0; k0 < C_; k0 += 32){
    __syncthreads();
    for (int rr = rr0; rr < 112; rr += 32){
      int row = t0 + rr;
      uint2 v = make_uint2(0u, 0u);
      if (row < NROW) v = *(const uint2*)(lanT + (size_t)row*C_ + k0 + kk);
      *(uint2*)&xs[rr*TPAD + kk] = v;
    }
    for (int rr = rr0; rr < 128; rr += 32)
      *(uint2*)&wsm[rr*TPAD + kk] = *(const uint2*)(wg + (size_t)rr*C_ + k0 + kk);
    __syncthreads();
    const short* pw0 = &wsm[(w*32 + lr)*TPAD + lg*4];
    const short* pw1 = &wsm[(w*32 + 16 + lr)*TPAD + lg*4];
    bhalf l0, h0;
    l0 = *(const bhalf*)pw0; h0 = *(const bhalf*)(pw0 + 16);
    bfrag bw0 = {l0[0],l0[1],l0[2],l0[3],h0[0],h0[1],h0[2],h0[3]};
    l0 = *(const bhalf*)pw1; h0 = *(const bhalf*)(pw1 + 16);
    bfrag bw1 = {l0[0],l0[1],l0[2],l0[3],h0[0],h0[1],h0[2],h0[3]};
    #pragma unroll
    for (int tf = 0; tf < 7; tf++){
      const short* pa = &xs[(tf*16 + lr)*TPAD + lg*4];
      bhalf al_ = *(const bhalf*)pa, ah_ = *(const bhalf*)(pa + 16);
      bfrag ax = {al_[0],al_[1],al_[2],al_[3],ah_[0],ah_[1],ah_[2],ah_[3]};
      acc[tf][0] = MFMA_B16(ax, bw0, acc[tf][0]);
      acc[tf][1] = MFMA_B16(ax, bw1, acc[tf][1]);
    }
  }
  bool isml = (wsel == 3);
  #pragma unroll
  for (int mf = 0; mf < 2; mf++){
    int m = m0 + w*32 + mf*16 + lr;
    float bv = isml ? 0.f : tb[wsel*C_ + m];
    #pragma unroll
    for (int tf = 0; tf < 7; tf++){
      #pragma unroll
      for (int r = 0; r < 4; r++){
        int row = t0 + tf*16 + lg*4 + r;
        if (row < NROW){
          float v = acc[tf][mf][r] + bv;
          if (!isml) v = fmaxf(v, 0.f);
          if (isml) lanML[(size_t)row*C_ + m] = v;
          else      QKVt[((size_t)wsel*NROW + row)*C_ + m] = v;
        }
      }
    }
  }
}

// fused: Mfix = exp(-Mt^2/(2 sigma^2)); Ppre[(b*HW+i)*MT+j] from Mfix
__global__ void k_mfixppre(const float* __restrict__ Mt, const float* __restrict__ hs2,
                           const float* __restrict__ W2, const float* __restrict__ b2,
                           const float* __restrict__ sc,
                           float* __restrict__ Mfix, float* __restrict__ Ppre){
  int idx = blockIdx.x*256 + threadIdx.x;
  if (idx >= B_*MT_*HW) return;
  int i = idx % HW;
  int j = (idx/HW) % MT_;
  int b = idx/(MT_*HW);
  float sig = 0.5f*(hs2[0] + hs2[1]);
  float v = Mt[idx];
  float f = expf(-v*v/(2.f*sig*sig));
  Mfix[idx] = f;
  float lam2s = 1.f/(1.f + expf(-sc[1]));
  Ppre[((size_t)b*HW + i)*MT_ + j] = lam2s*f + (1.f - lam2s)*(W2[i*MT_ + j]*f + b2[i*MT_ + j]);
}

__global__ __launch_bounds__(256) void k_sm20(const float* __restrict__ Ppre, float* __restrict__ Pi2t){
  int row = blockIdx.x*8 + (threadIdx.x >> 5);
  int lane = threadIdx.x & 31;
  if (row >= B_*HW) return;
  float v = (lane < MT_) ? Ppre[(size_t)row*MT_ + lane]*(1.f/SQC) : -3.4e38f;
  float m = v;
  for (int o = 16; o > 0; o >>= 1) m = fmaxf(m, __shfl_xor(m, o, 32));
  float e = (lane < MT_) ? expf(v - m) : 0.f;
  float s = e;
  for (int o = 16; o > 0; o >>= 1) s += __shfl_xor(s, o, 32);
  if (lane < MT_) Pi2t[(size_t)row*MT_ + lane] = e/s;
}

__global__ __launch_bounds__(128) void k_smT(const float* __restrict__ Ppre, float* __restrict__ Pt2i){
  __shared__ float sm[128], ss[128];
  int bj = blockIdx.x; int b = bj/MT_, j = bj % MT_;
  int i = threadIdx.x;
  float v = (i < HW) ? Ppre[((size_t)b*HW + i)*MT_ + j]*(1.f/SQC) : -3.4e38f;
  sm[i] = v; __syncthreads();
  for (int o = 64; o > 0; o >>= 1){
    if (i < o) sm[i] = fmaxf(sm[i], sm[i+o]);
    __syncthreads();
  }
  float m = sm[0];
  float e = (i < HW) ? expf(v - m) : 0.f;
  ss[i] = e; __syncthreads();
  for (int o = 64; o > 0; o >>= 1){
    if (i < o) ss[i] += ss[i+o];
    __syncthreads();
  }
  if (i < HW) Pt2i[((size_t)b*MT_ + j)*HW + i] = e/ss[0];
}

// merged mlearn_t2i + t2 (same math/order as the two originals; one launch)
__global__ __launch_bounds__(256) void k_mlearn2(const float* __restrict__ Pi2t,
    const float* __restrict__ Pt2i, const float* __restrict__ lanML,
    const float* __restrict__ mlb, const float* __restrict__ feat,
    float* __restrict__ outMl, float* __restrict__ T2o){
  __shared__ float sP[HW][MT_];
  __shared__ float sQ[MT_][HW];
  int b = blockIdx.y; int m = blockIdx.x*256 + threadIdx.x;
  for (int e = threadIdx.x; e < HW*MT_; e += 256){
    sP[e/MT_][e%MT_] = Pi2t[(size_t)b*HW*MT_ + e];
    sQ[e/HW][e%HW]   = Pt2i[(size_t)b*MT_*HW + e];
  }
  __syncthreads();
  float vL[MT_];
  #pragma unroll
  for (int j = 0; j < MT_; j++) vL[j] = lanML[((size_t)b*MT_ + j)*C_ + m];
  float accT[MT_];
  #pragma unroll
  for (int j = 0; j < MT_; j++) accT[j] = 0.f;
  float bb = mlb[m];
  for (int i = 0; i < HW; i++){
    float f = feat[((size_t)b*HW + i)*C_ + m];
    float a = bb;
    #pragma unroll
    for (int j = 0; j < MT_; j++){
      a += sP[i][j]*vL[j];
      accT[j] += sQ[j][i]*f;
    }
    outMl[((size_t)b*HW + i)*C_ + m] = a;
  }
  #pragma unroll
  for (int j = 0; j < MT_; j++) T2o[((size_t)b*MT_ + j)*C_ + m] = accT[j];
}

// W4Ml[b][q][c] = sum_p W4[q][p] * Ml[b][p][c]   (associativity restructure)
__global__ __launch_bounds__(256) void k_w4ml(const float* __restrict__ W4,
    const float* __restrict__ Ml, float* __restrict__ out){
  __shared__ float sW[MT_][HW];
  int b = blockIdx.y; int m = blockIdx.x*256 + threadIdx.x;
  for (int e = threadIdx.x; e < MT_*HW; e += 256) sW[e/HW][e%HW] = W4[e];
  __syncthreads();
  float acc[MT_];
  #pragma unroll
  for (int j = 0; j < MT_; j++) acc[j] = 0.f;
  for (int p = 0; p < HW; p++){
    float f = Ml[((size_t)b*HW + p)*C_ + m];
    #pragma unroll
    for (int j = 0; j < MT_; j++) acc[j] += sW[j][p]*f;
  }
  #pragma unroll
  for (int j = 0; j < MT_; j++) out[((size_t)b*MT_ + j)*C_ + m] = acc[j];
}

__global__ __launch_bounds__(256) void k_abt(const float* __restrict__ X,
    const float* __restrict__ Y, float* __restrict__ out, int I, int Jd){
  __shared__ float Xs[16][33], Ys[64][33];
  int i0 = blockIdx.x*16, j0 = blockIdx.y*64, b = blockIdx.z;
  int jl = threadIdx.x & 63, ig = threadIdx.x >> 6;
  float acc[4] = {0.f,0.f,0.f,0.f};
  const float* Xb = X + (size_t)b*I*C_;
  const float* Yb = Y + (size_t)b*Jd*C_;
  for (int c0 = 0; c0 < C_; c0 += 32){
    for (int e = threadIdx.x; e < 512; e += 256){
      int r = e >> 5, cc = e & 31;
      Xs[r][cc] = (i0+r < I) ? Xb[(size_t)(i0+r)*C_ + c0+cc] : 0.f;
    }
    for (int e = threadIdx.x; e < 2048; e += 256){
      int r = e >> 5, cc = e & 31;
      Ys[r][cc] = (j0+r < Jd) ? Yb[(size_t)(j0+r)*C_ + c0+cc] : 0.f;
    }
    __syncthreads();
    for (int kk = 0; kk < 32; kk++){
      float y = Ys[jl][kk];
      #pragma unroll
      for (int k = 0; k < 4; k++) acc[k] += Xs[ig*4+k][kk]*y;
    }
    __syncthreads();
  }
  #pragma unroll
  for (int k = 0; k < 4; k++){
    int i = i0 + ig*4 + k, j = j0 + jl;
    if (i < I && j < Jd) out[((size_t)b*I + i)*Jd + j] = acc[k];
  }
}

// fused double-B k_abt: out1 = X@Y1^T, out2 = X@Y2^T (shared A read).
__global__ __launch_bounds__(256) void k_abt2(const float* __restrict__ X,
    const float* __restrict__ Y1, const float* __restrict__ Y2,
    float* __restrict__ out1, float* __restrict__ out2, int I, int Jd){
  __shared__ float Xs[16][33], Y1s[64][33], Y2s[64][33];
  int i0 = blockIdx.x*16, j0 = blockIdx.y*64, b = blockIdx.z;
  int jl = threadIdx.x & 63, ig = threadIdx.x >> 6;
  float acc1[4] = {0.f,0.f,0.f,0.f};
  float acc2[4] = {0.f,0.f,0.f,0.f};
  const float* Xb  = X  + (size_t)b*I*C_;
  const float* Y1b = Y1 + (size_t)b*Jd*C_;
  const float* Y2b = Y2 + (size_t)b*Jd*C_;
  for (int c0 = 0; c0 < C_; c0 += 32){
    for (int e = threadIdx.x; e < 512; e += 256){
      int r = e >> 5, cc = e & 31;
      Xs[r][cc] = (i0+r < I) ? Xb[(size_t)(i0+r)*C_ + c0+cc] : 0.f;
    }
    for (int e = threadIdx.x; e < 2048; e += 256){
      int r = e >> 5, cc = e & 31;
      bool ok = (j0+r < Jd);
      Y1s[r][cc] = ok ? Y1b[(size_t)(j0+r)*C_ + c0+cc] : 0.f;
      Y2s[r][cc] = ok ? Y2b[(size_t)(j0+r)*C_ + c0+cc] : 0.f;
    }
    __syncthreads();
    for (int kk = 0; kk < 32; kk++){
      float y1 = Y1s[jl][kk], y2 = Y2s[jl][kk];
      #pragma unroll
      for (int k = 0; k < 4; k++){
        float x = Xs[ig*4+k][kk];
        acc1[k] += x*y1;
        acc2[k] += x*y2;
      }
    }
    __syncthreads();
  }
  #pragma unroll
  for (int k = 0; k < 4; k++){
    int i = i0 + ig*4 + k, j = j0 + jl;
    if (i < I && j < Jd){
      out1[((size_t)b*I + i)*Jd + j] = acc1[k];
      out2[((size_t)b*I + i)*Jd + j] = acc2[k];
    }
  }
}

// attA (+fused lossA): S3n is now precomputed [B,MT,HW] -> pure elementwise.
__global__ __launch_bounds__(128) void k_attA(const float* __restrict__ S1,
    const float* __restrict__ S2, const float* __restrict__ S3n,
    const float* __restrict__ sc, const float* __restrict__ Mfix,
    float* __restrict__ Av, float* __restrict__ pa){
  __shared__ float red[128];
  int bq = blockIdx.x;
  int j = threadIdx.x;
  float a1 = sc[2], be1 = sc[3];
  float v = -3.4e38f;
  if (j < HW){
    size_t off = (size_t)bq*HW + j;
    v = (S1[off] + a1*S2[off] + be1*S3n[off])*(1.f/SQC);
  }
  red[j] = v; __syncthreads();
  for (int o = 64; o > 0; o >>= 1){
    if (j < o) red[j] = fmaxf(red[j], red[j+o]);
    __syncthreads();
  }
  float m = red[0]; __syncthreads();
  float e = (j < HW) ? expf(v - m) : 0.f;
  red[j] = e; __syncthreads();
  for (int o = 64; o > 0; o >>= 1){
    if (j < o) red[j] += red[j+o];
    __syncthreads();
  }
  float av = (j < HW) ? e/red[0] : 0.f;
  if (j < HW) Av[(size_t)bq*HW + j] = av;
  __syncthreads();
  // ---- loss part ----
  float vm = (j < HW) ? Mfix[(size_t)bq*HW + j]*(1.f/SQC) : -3.4e38f;
  red[j] = vm; __syncthreads();
  for (int o = 64; o > 0; o >>= 1){
    if (j < o) red[j] = fmaxf(red[j], red[j+o]);
    __syncthreads();
  }
  float mm = red[0]; __syncthreads();
  float em = (j < HW) ? expf(vm - mm) : 0.f;
  red[j] = em; __syncthreads();
  for (int o = 64; o > 0; o >>= 1){
    if (j < o) red[j] += red[j+o];
    __syncthreads();
  }
  float fa = (j < HW) ? em/red[0] : 0.f;
  __syncthreads();
  float p[5] = { fabsf(av - fa), av, av*av, fa, fa*fa };
  for (int s = 0; s < 5; s++){
    red[j] = p[s]; __syncthreads();
    for (int o = 64; o > 0; o >>= 1){
      if (j < o) red[j] += red[j+o];
      __syncthreads();
    }
    if (j == 0) pa[bq*5 + s] = red[0];
    __syncthreads();
  }
}

// attB (+fused lossB)
__global__ __launch_bounds__(256) void k_attB(const float* __restrict__ S4a,
    const float* __restrict__ S4b, const float* __restrict__ S5,
    const float* __restrict__ W5, const float* __restrict__ sc,
    const float* __restrict__ Mfix, float* __restrict__ Bv, float* __restrict__ pb){
  __shared__ float red[8];
  int row = blockIdx.x*8 + (threadIdx.x >> 5);
  int lane = threadIdx.x & 31;
  int b = row/HW, i = row % HW;
  float a2 = sc[5], be2 = sc[6];
  float v = -3.4e38f;
  if (lane < MT_){
    float s5 = 0.f;
    const float* S5b = S5 + (size_t)b*MT_*MT_ + lane;
    const float* w5 = W5 + (size_t)i*MT_;
    #pragma unroll
    for (int p = 0; p < MT_; p++) s5 += w5[p]*S5b[p*MT_];
    size_t off = (size_t)row*MT_ + lane;
    v = (S4a[off] + a2*S4b[off] + be2*s5)*(1.f/SQC);
  }
  float m = v;
  for (int o = 16; o > 0; o >>= 1) m = fmaxf(m, __shfl_xor(m, o, 32));
  float e = (lane < MT_) ? expf(v - m) : 0.f;
  float s = e;
  for (int o = 16; o > 0; o >>= 1) s += __shfl_xor(s, o, 32);
  float bv = (lane < MT_) ? e/s : 0.f;
  if (lane < MT_) Bv[(size_t)row*MT_ + lane] = bv;
  // ---- loss part ----
  float vm = (lane < MT_) ? Mfix[((size_t)b*MT_ + lane)*HW + i]*(1.f/SQC) : -3.4e38f;
  float mm = vm;
  for (int o = 16; o > 0; o >>= 1) mm = fmaxf(mm, __shfl_xor(mm, o, 32));
  float em = (lane < MT_) ? expf(vm - mm) : 0.f;
  float sm = em;
  for (int o = 16; o > 0; o >>= 1) sm += __shfl_xor(sm, o, 32);
  float fb = (lane < MT_) ? em/sm : 0.f;
  float p[5] = { fabsf(bv - fb), bv, bv*bv, fb, fb*fb };
  for (int s5 = 0; s5 < 5; s5++){
    float x = p[s5];
    for (int o = 16; o > 0; o >>= 1) x += __shfl_xor(x, o, 32);
    if (lane == 0) red[threadIdx.x >> 5] = x;
    __syncthreads();
    if (threadIdx.x == 0){
      float t = 0.f;
      for (int g = 0; g < 8; g++) t += red[g];
      pb[blockIdx.x*5 + s5] = t;
    }
    __syncthreads();
  }
}

__global__ __launch_bounds__(256) void k_nl(const float* __restrict__ Av,
    const float* __restrict__ Pt2i, const float* __restrict__ Vf,
    const float* __restrict__ sc, float* __restrict__ NL){
  __shared__ float sA[MT_][HW];
  int b = blockIdx.y; int m = blockIdx.x*256 + threadIdx.x;
  float g1 = sc[4];
  for (int e = threadIdx.x; e < MT_*HW; e += 256)
    sA[e/HW][e%HW] = Av[(size_t)b*MT_*HW + e] + g1*Pt2i[(size_t)b*MT_*HW + e];
  __syncthreads();
  float acc[MT_];
  #pragma unroll
  for (int q = 0; q < MT_; q++) acc[q] = 0.f;
  for (int k = 0; k < HW; k++){
    float v = Vf[((size_t)b*HW + k)*C_ + m];
    #pragma unroll
    for (int q = 0; q < MT_; q++) acc[q] += sA[q][k]*v;
  }
  #pragma unroll
  for (int q = 0; q < MT_; q++) NL[((size_t)b*MT_ + q)*C_ + m] = acc[q];
}

// NV in bf16 (sole consumer is k_convout_mfma)
__global__ __launch_bounds__(256) void k_nv(const float* __restrict__ Bv,
    const float* __restrict__ Pi2t, const float* __restrict__ Vt,
    const float* __restrict__ sc, short* __restrict__ NVb){
  __shared__ float sB[HW][MT_];
  int b = blockIdx.y; int m = blockIdx.x*256 + threadIdx.x;
  float g2 = sc[7];
  for (int e = threadIdx.x; e < HW*MT_; e += 256)
    sB[e/MT_][e%MT_] = Bv[(size_t)b*HW*MT_ + e] + g2*Pi2t[(size_t)b*HW*MT_ + e];
  __syncthreads();
  float vT[MT_];
  #pragma unroll
  for (int j = 0; j < MT_; j++) vT[j] = Vt[((size_t)b*MT_ + j)*C_ + m];
  for (int i = 0; i < HW; i++){
    float a = 0.f;
    #pragma unroll
    for (int j = 0; j < MT_; j++) a += sB[i][j]*vT[j];
    NVb[((size_t)b*HW + i)*C_ + m] = f2bf(a);
  }
}

__global__ __launch_bounds__(256) void k_loss_final(const float* __restrict__ pa,
    const float* __restrict__ pb, float* __restrict__ outloss){
  __shared__ float red[256];
  float s[5] = {0,0,0,0,0}, t[5] = {0,0,0,0,0};
  for (int r = threadIdx.x; r < 1280; r += 256)
    for (int k = 0; k < 5; k++) s[k] += pa[r*5 + k];
  for (int r = threadIdx.x; r < 800; r += 256)
    for (int k = 0; k < 5; k++) t[k] += pb[r*5 + k];
  float res[10];
  for (int k = 0; k < 5; k++){
    red[threadIdx.x] = s[k]; __syncthreads();
    for (int o = 128; o > 0; o >>= 1){
      if ((int)threadIdx.x < o) red[threadIdx.x] += red[threadIdx.x+o];
      __syncthreads();
    }
    res[k] = red[0]; __syncthreads();
  }
  for (int k = 0; k < 5; k++){
    red[threadIdx.x] = t[k]; __syncthreads();
    for (int o = 128; o > 0; o >>= 1){
      if ((int)threadIdx.x < o) red[threadIdx.x] += red[threadIdx.x+o];
      __syncthreads();
    }
    res[5+k] = red[0]; __syncthreads();
  }
  if (threadIdx.x == 0){
    const float n = 128000.f;
    float l1 = res[0]/n + res[5]/n;
    float varAv = (res[2] - res[1]*res[1]/n)/(n - 1.f);
    float varfA = (res[4] - res[3]*res[3]/n)/(n - 1.f);
    float varBv = (res[7] - res[6]*res[6]/n)/(n - 1.f);
    float varfB = (res[9] - res[8]*res[8]/n)/(n - 1.f);
    float l2 = -fabsf(varAv - varfA) - fabsf(varBv - varfB);
    outloss[0] = (l1 + 100.f*l2)*1000.f;
  }
}

// ---------------- launcher ----------------
extern "C" void kernel_launch(void* const* d_in, const int* in_sizes, int n_in,
                              void* d_out, int out_size, void* d_ws, size_t ws_size,
                              hipStream_t stream){
  const float* ir     = (const float*)d_in[0];
  const float* vis    = (const float*)d_in[1];
  const float* lan    = (const float*)d_in[2];
  const float* vis_w  = (const float*)d_in[3];
  const float* vis_g  = (const float*)d_in[5];
  const float* vis_be = (const float*)d_in[6];
  const float* ir_w   = (const float*)d_in[7];
  const float* ir_g   = (const float*)d_in[9];
  const float* ir_be  = (const float*)d_in[10];
  const float* t_w    = (const float*)d_in[11];
  const float* t_b    = (const float*)d_in[12];
  const float* vout_w = (const float*)d_in[13];
  const float* vout_b = (const float*)d_in[14];
  const float* tout_w = (const float*)d_in[15];
  const float* tout_b = (const float*)d_in[16];
  const float* W1     = (const float*)d_in[17];
  const float* b1     = (const float*)d_in[18];
  const float* W2     = (const float*)d_in[19];
  const float* b2     = (const float*)d_in[20];
  const float* W4     = (const float*)d_in[21];
  const float* W5     = (const float*)d_in[22];
  const float* ml_w   = (const float*)d_in[23];
  const float* ml_b   = (const float*)d_in[24];
  const float* ml2_w  = (const float*)d_in[25];
  const float* ml2_b  = (const float*)d_in[26];
  const float* sc     = (const float*)d_in[27];

  float* ws = (float*)d_ws;
  float* J     = ws + F_J;
  float* Dm    = ws + F_D;
  float* sqb   = ws + F_SQ;
  float* Mv    = ws + F_MV;
  float* Mt    = ws + F_MT;
  float* Mfix  = ws + F_MFIX;
  float* QKVf  = ws + F_QKVF;
  float* QKVt  = ws + F_QKVT;
  float* feat  = ws + F_FEAT;
  float* lanML = ws + F_LANML;
  float* T2b   = ws + F_T2;
  float* Mi2tL = ws + F_MI2TL;
  float* S1    = ws + F_S1;
  float* S2    = ws + F_S2;
  float* S4a   = ws + F_S4A;
  float* S4b   = ws + F_S4B;
  float* S5    = ws + F_S5;
  float* Av    = ws + F_AV;
  float* Bv    = ws + F_BV;
  float* NL    = ws + F_NL;
  float* alpha = ws + F_AL;
  float* bet   = ws + F_BE;
  float* hs    = ws + F_HS;
  unsigned* hist = (unsigned*)(ws + F_HIST);
  float* pa    = ws + F_PA;
  float* pb    = ws + F_PB;
  // overlays
  float* MlT2I = ws + F_J;
  float* S3n   = ws + F_D;
  float* W4Ml  = ws + F_T2;          // T2b dead after tokproj
  float* Pi2t  = ws + F_MV;
  float* Pt2i  = ws + F_MV + 128000;
  float* Ppre  = ws + F_MV + 256000;
  // bf16 overlays (lifetimes disjoint — see layout comment)
  short* XtV    = (short*)(ws + F_J);
  short* XtI    = (short*)(ws + F_J + 3300000);
  short* WVb    = (short*)(ws + F_J + 6600000);
  short* WIb    = (short*)(ws + F_J + 8200000);
  short* NVb    = (short*)(ws + F_J + 6553600);
  short* Wob16  = (short*)(ws + F_J + 9830400);
  short* lanTb  = (short*)(ws + F_J + 10360000);
  short* Wtb    = (short*)(ws + F_D);
  short* tout16 = (short*)(ws + F_D + 1000000);
  short* ml2w16 = (short*)(ws + F_D + 1530000);

  float* out_vis  = (float*)d_out;
  float* out_lan  = out_vis + (size_t)B_*C_*HW;
  float* out_loss = out_lan + (size_t)B_*MT_*C_;

  float* Qf = QKVf;
  float* Kf = QKVf + (size_t)B_*HW*C_;
  float* Vf = QKVf + (size_t)2*B_*HW*C_;
  float* Qt = QKVt;
  float* Kt = QKVt + (size_t)B_*MT_*C_;
  float* Vt = QKVt + (size_t)2*B_*MT_*C_;

  // ---- geodesic 1 (vis ++ ir) ----
  k_pack_j1<<<dim3(32,7,B_),256,0,stream>>>(vis, ir, J);
  k_rowsq<<<B_*P1,64,0,stream>>>(J, sqb, P1);
  k_gram_dist<<<dim3(4,4,B_),256,0,stream>>>(J, sqb, Dm, P1);
  k_fwx<P1,1024,10,4,0,100,100,100><<<B_,1024,0,stream>>>(Dm, Mv, hs, hist);
  for (int it = 0; it < 2; it++){
    k_med_hist<<<256,256,0,stream>>>(Mv, B_*HW*HW, hs, hist);
    k_med_select<<<1,64,0,stream>>>(hs, hist, B_*HW*HW/2);
  }
  k_mgap<<<B_,256,0,stream>>>(Mv, W1, b1, sc, hs, alpha, bet);

  // ---- projections (bf16 MFMA paths) ----
  k_castw<<<(3*C_*C_/4+255)/256,256,0,stream>>>(vis_w, ir_w, WVb, WIb);
  k_cast<<<(C_*C_/4+255)/256,256,0,stream>>>(vout_w, Wob16, C_*C_);
  k_cast2<<<((4*C_*C_)/4+255)/256,256,0,stream>>>(t_w, ml_w, Wtb,
                                                  Wtb + (size_t)3*C_*C_,
                                                  3*C_*C_, C_*C_);
  k_xt2<<<dim3(32,4,B_),256,0,stream>>>(vis, ir, alpha, bet, XtV, XtI, feat);
  k_lanT<<<dim3(32,B_),256,0,stream>>>(lan, lanTb);
  k_convqkv_mfma<<<dim3(8,3,B_),256,0,stream>>>(XtV, XtI, WVb, WIb,
                                                vis_g, vis_be, ir_g, ir_be,
                                                alpha, bet, QKVf);
  k_textproj_mfma<<<dim3(8,12,4),256,0,stream>>>(lanTb, Wtb, t_b, QKVt, lanML);
  // Wtb dead now; cast late-GEMM weights into upper Dm region (audited free).
  k_cast2<<<((2*C_*C_)/4+255)/256,256,0,stream>>>(tout_w, ml2_w, tout16, ml2w16,
                                                  C_*C_, C_*C_);

  // ---- geodesic 2 (feat ++ lan) ----
  k_pack_j2<<<(B_*P2*C_+255)/256,256,0,stream>>>(feat, lan, J);
  k_rowsq<<<B_*P2,64,0,stream>>>(J, sqb, P2);
  k_gram_dist<<<dim3(2,2,B_),256,0,stream>>>(J, sqb, Dm, P2);
  k_fwx<P2,960,4,4,100,0,MT_,100><<<B_,960,0,stream>>>(Dm, Mt, hs+2, hist);
  for (int it = 0; it < 2; it++){
    k_med_hist<<<256,256,0,stream>>>(Mt, B_*MT_*HW, hs+2, hist);
    k_med_select<<<1,64,0,stream>>>(hs+2, hist, B_*MT_*HW/2);
  }
  k_mfixppre<<<(B_*MT_*HW+255)/256,256,0,stream>>>(Mt, hs+2, W2, b2, sc, Mfix, Ppre);
  k_sm20<<<(B_*HW+7)/8,256,0,stream>>>(Ppre, Pi2t);
  k_smT<<<B_*MT_,128,0,stream>>>(Ppre, Pt2i);

  // ---- manifold-learned matrices ----
  k_mlearn2<<<dim3(4,B_),256,0,stream>>>(Pi2t, Pt2i, lanML, ml_b, feat, MlT2I, T2b);
  k_tokproj_mfma<<<dim3(8,12),256,0,stream>>>(T2b, ml2w16, ml2_b, Mi2tL);

  // ---- attention scores (+ fused loss partials) ----
  k_w4ml<<<dim3(4,B_),256,0,stream>>>(W4, MlT2I, W4Ml);
  k_abt2<<<dim3(2,2,B_),256,0,stream>>>(Qt, Kf, MlT2I, S1, S2, MT_, HW);
  k_abt<<<dim3(2,2,B_),256,0,stream>>>(W4Ml, Kf, S3n, MT_, HW);
  k_abt2<<<dim3(7,1,B_),256,0,stream>>>(Qf, Kt, Mi2tL, S4a, S4b, HW, MT_);
  k_abt<<<dim3(2,1,B_),256,0,stream>>>(Mi2tL, Kt, S5, MT_, MT_);
  k_attA<<<B_*MT_,128,0,stream>>>(S1, S2, S3n, sc, Mfix, Av, pa);
  k_attB<<<B_*HW/8,256,0,stream>>>(S4a, S4b, S5, W5, sc, Mfix, Bv, pb);

  // ---- outputs ----
  k_nl<<<dim3(4,B_),256,0,stream>>>(Av, Pt2i, Vf, sc, NL);
  k_nv<<<dim3(4,B_),256,0,stream>>>(Bv, Pi2t, Vt, sc, NVb);
  k_tokproj_mfma<<<dim3(8,12),256,0,stream>>>(NL, tout16, tout_b, out_lan);
  k_convout_mfma<<<dim3(8,B_),256,0,stream>>>(NVb, Wob16, vout_b, out_vis);

  // ---- loss ----
  k_loss_final<<<1,256,0,stream>>>(pa, pb, out_loss);
}

// Round 19
// 2649.809 us; speedup vs baseline: 1.0349x; 1.0349x over previous
//
#include <hip/hip_runtime.h>
#include <hip/hip_bf16.h>
#include <math.h>

#define B_   64
#define C_   1024
#define HW   100
#define MT_  20
#define P1   200
#define P2   120
#define BIGF 1.0e6f
#define EPSF 1e-8f
#define SQC  32.0f

// ---------------- workspace layout (float offsets) ----------------
static constexpr size_t F_J    = 0;
static constexpr size_t N_J    = (size_t)B_*P1*C_;        // 13,107,200
static constexpr size_t F_D    = F_J + N_J;
static constexpr size_t N_D    = (size_t)B_*P1*P1;        // 2,560,000
static constexpr size_t F_SQ   = F_D + N_D;
static constexpr size_t N_SQ   = (size_t)B_*P1;
static constexpr size_t F_KNN  = F_SQ + N_SQ;
static constexpr size_t N_KNN  = (size_t)B_*P1*8;
static constexpr size_t F_MV   = F_KNN + N_KNN;
static constexpr size_t N_MV   = (size_t)B_*HW*HW;
static constexpr size_t F_MT   = F_MV + N_MV;
static constexpr size_t N_SM   = (size_t)B_*MT_*HW;
static constexpr size_t F_MFIX = F_MT + N_SM;
static constexpr size_t F_QKVF = F_MFIX + N_SM;
static constexpr size_t N_QKVF = (size_t)3*B_*HW*C_;
static constexpr size_t F_QKVT = F_QKVF + N_QKVF;
static constexpr size_t N_QKVT = (size_t)3*B_*MT_*C_;
static constexpr size_t F_FEAT = F_QKVT + N_QKVT;
static constexpr size_t N_FEAT = (size_t)B_*HW*C_;
static constexpr size_t N_SMC  = (size_t)B_*MT_*C_;
static constexpr size_t F_LANML= F_FEAT + N_FEAT;
static constexpr size_t F_T2   = F_LANML + N_SMC;
static constexpr size_t F_MI2TL= F_T2 + N_SMC;
static constexpr size_t F_S1   = F_MI2TL + N_SMC;
static constexpr size_t F_S2   = F_S1 + N_SM;
static constexpr size_t F_S4A  = F_S2 + N_SM;
static constexpr size_t F_S4B  = F_S4A + N_SM;
static constexpr size_t F_S5   = F_S4B + N_SM;
static constexpr size_t F_AV   = F_S5 + (size_t)B_*MT_*MT_;
static constexpr size_t F_BV   = F_AV + N_SM;
static constexpr size_t F_NL   = F_BV + N_SM;
static constexpr size_t F_AL   = F_NL + N_SMC;
static constexpr size_t F_BE   = F_AL + 64;
static constexpr size_t F_HS   = F_BE + 64;
static constexpr size_t F_HIST = F_HS + 8;
static constexpr size_t F_PA   = F_HIST + 1032;
static constexpr size_t F_PB   = F_PA + 6400;
// overlays: MlT2I = F_J [0..6,553,600) ; S3n = F_D [..128,000)
//           Pi2t = F_MV ; Pt2i = F_MV+128000 ; Ppre = F_MV+256000
//           W4Ml = F_T2 (T2b dead after tokproj)
// bf16 overlays (fl offsets; lifetimes audited disjoint):
//   XtV  = F_J          [0 .. 3,276,800)        [k_xt2 .. convqkv]
//   XtI  = +3,300,000   [.. 6,576,800)          [k_xt2 .. convqkv]
//   WVb  = +6,600,000   [.. 8,172,864)          [castw .. convqkv]
//   WIb  = +8,200,000   [.. 9,772,864)          [castw .. convqkv]
//   NVb  = +6,553,600   [.. 9,830,400)          [k_nv .. convout]
//   Wob16= +9,830,400   [.. 10,354,688)         [k_cast .. convout]
//   lanTb= +10,360,000  [.. 11,015,360)         [k_lanT .. textproj]
//   Wtb  = F_D          [.. F_D+2,097,152)      [k_cast .. textproj]
//   tout16 = F_D+1,000,000 ; ml2w16 = F_D+1,530,000  [post-textproj .. late gemms]
//     (S3n <= 128,000 fl -> disjoint from tout16/ml2w16)

typedef __attribute__((ext_vector_type(8))) short bfrag;
typedef __attribute__((ext_vector_type(4))) short bhalf;
typedef __attribute__((ext_vector_type(4))) float f32x4;
#define MFMA_B16(a,b,c) __builtin_amdgcn_mfma_f32_16x16x32_bf16(a,b,c,0,0,0)

__device__ inline short f2bf(float x){
  __hip_bfloat16 h = __float2bfloat16(x);
  return *reinterpret_cast<short*>(&h);
}

// ---------------- kernels ----------------

// LDS-tiled pack: J[b][p][c] = (p<HW ? vis : ir)[b][c][p(-HW)], both sides coalesced.
__global__ __launch_bounds__(256) void k_pack_j1(const float* __restrict__ vis,
    const float* __restrict__ ir, float* __restrict__ J){
  __shared__ float tile[32][33];
  int c0 = blockIdx.x*32, p0 = blockIdx.y*32, b = blockIdx.z;
  int j = threadIdx.x & 31, i0 = threadIdx.x >> 5;
  for (int i = i0; i < 32; i += 8){
    int p = p0 + j;
    float v = 0.f;
    if (p < P1) v = (p < HW) ? vis[((size_t)b*C_ + c0+i)*HW + p]
                             : ir [((size_t)b*C_ + c0+i)*HW + (p-HW)];
    tile[i][j] = v;
  }
  __syncthreads();
  for (int i = i0; i < 32; i += 8){
    int p = p0 + i;
    if (p < P1) J[((size_t)b*P1 + p)*C_ + c0 + j] = tile[j][i];
  }
}

__global__ void k_pack_j2(const float* __restrict__ feat, const float* __restrict__ lan,
                          float* __restrict__ J){
  int idx = blockIdx.x*256 + threadIdx.x;
  if (idx >= B_*P2*C_) return;
  int c = idx & (C_-1);
  int p = (idx >> 10) % P2;
  int b = idx / (C_*P2);
  float v;
  if (p < HW) v = feat[((size_t)b*HW + p)*C_ + c];
  else        v = lan [((size_t)b*C_ + c)*MT_ + (p-HW)];
  J[idx] = v;
}

__global__ void k_rowsq(const float* __restrict__ J, float* __restrict__ sq, int P){
  int row = blockIdx.x;
  const float* r = J + (size_t)row*C_;
  float s = 0.f;
  for (int c = threadIdx.x; c < C_; c += 64){ float v = r[c]; s += v*v; }
  for (int o = 32; o > 0; o >>= 1) s += __shfl_down(s, o);
  if (threadIdx.x == 0) sq[row] = s;
}

// 64x64 tile, 4x4 acc, TRANSPOSED LDS [kk][row] (pad 68 => 16B-aligned b128
// reads; conflict-free read path). Same per-element kk order as original =>
// bit-identical distances (kNN-safe).
__global__ __launch_bounds__(256) void k_gram_dist(const float* __restrict__ J,
    const float* __restrict__ sq, float* __restrict__ D, int P){
  __shared__ __align__(16) float Xi[32][68];
  __shared__ __align__(16) float Xj[32][68];
  int b = blockIdx.z;
  int r0 = blockIdx.x*64, s0 = blockIdx.y*64;
  int tx = threadIdx.x & 15, ty = threadIdx.x >> 4;
  const float* Jb = J + (size_t)b*P*C_;
  float acc[4][4];
  #pragma unroll
  for (int u = 0; u < 4; u++)
    #pragma unroll
    for (int v = 0; v < 4; v++) acc[u][v] = 0.f;
  for (int c0 = 0; c0 < C_; c0 += 32){
    for (int e = threadIdx.x; e < 2048; e += 256){
      int rr = e >> 5, cc = e & 31;
      Xi[cc][rr] = (r0+rr < P) ? Jb[(size_t)(r0+rr)*C_ + c0+cc] : 0.f;
      Xj[cc][rr] = (s0+rr < P) ? Jb[(size_t)(s0+rr)*C_ + c0+cc] : 0.f;
    }
    __syncthreads();
    for (int kk = 0; kk < 32; kk++){
      float4 xr4 = *(const float4*)&Xi[kk][ty*4];
      float4 xs4 = *(const float4*)&Xj[kk][tx*4];
      float xr[4] = {xr4.x, xr4.y, xr4.z, xr4.w};
      float xs[4] = {xs4.x, xs4.y, xs4.z, xs4.w};
      #pragma unroll
      for (int u = 0; u < 4; u++)
        #pragma unroll
        for (int v = 0; v < 4; v++) acc[u][v] += xr[u]*xs[v];
    }
    __syncthreads();
  }
  #pragma unroll
  for (int u = 0; u < 4; u++){
    #pragma unroll
    for (int v = 0; v < 4; v++){
      int r = r0 + ty*4 + u, s = s0 + tx*4 + v;
      if (r < P && s < P){
        float d2 = sq[b*P+r] + sq[b*P+s] - 2.f*acc[u][v];
        D[((size_t)b*P + r)*P + s] = sqrtf(fmaxf(d2, 0.f));
      }
    }
  }
}

// wave-parallel kNN (round-17 proven version: ~40us total)
template<int P>
__global__ void k_knn(const float* __restrict__ D, int* __restrict__ knn){
  constexpr int NS = (P + 63)/64;
  int row = blockIdx.x;
  int i = row % P;
  const float* Dr = D + (size_t)row*P;
  float v[NS];
  #pragma unroll
  for (int t = 0; t < NS; t++){
    int j = threadIdx.x + t*64;
    float d = (j < P) ? Dr[j] : 4.0e6f;
    if (j == i) d += BIGF;
    v[t] = d;
  }
  for (int k = 0; k < 8; k++){
    float bv = 3.4e38f; int bj = 1 << 30;
    #pragma unroll
    for (int t = 0; t < NS; t++){
      int j = threadIdx.x + t*64;
      if (v[t] < bv){ bv = v[t]; bj = j; }
    }
    for (int o = 32; o > 0; o >>= 1){
      float ov = __shfl_xor(bv, o);
      int   oj = __shfl_xor(bj, o);
      if (ov < bv || (ov == bv && oj < bj)){ bv = ov; bj = oj; }
    }
    if (threadIdx.x == 0) knn[(size_t)row*8 + k] = bj;
    if ((bj & 63) == (int)threadIdx.x){
      #pragma unroll
      for (int t = 0; t < NS; t++) if (t == (bj >> 6)) v[t] = 3.9e38f;
    }
  }
}

// Fused buildw + register-FW + minmax(window) -> normalized output.
// knn read from global (wave-parallel kernel); block 0 also zeroes the median
// histogram and seeds hs (removes memset/init launches).
template<int P, int NT, int RP, int CP, int R0, int C0, int RR, int CC>
__global__ __launch_bounds__(1024) void k_fwx(const float* __restrict__ D,
    const int* __restrict__ knn, float* __restrict__ outM,
    float* __restrict__ hs, unsigned* __restrict__ hist){
  constexpr int PR = P/RP;
  constexpr int PC = P/CP;
  constexpr int NTH = PR*PC;
  __shared__ float rowk[P], colk[P];
  __shared__ int kl[P*8];
  __shared__ float rmn[1024], rmx[1024];
  int b = blockIdx.x;
  const float* Db = D + (size_t)b*P*P;
  const int* kb = knn + (size_t)b*P*8;
  int tid = threadIdx.x;
  if (b == 0){
    for (int e = tid; e < 1025; e += NT) hist[e] = 0u;
    if (tid == 0){ hs[0] = 0.f; hs[1] = 1.0f; }
  }
  for (int e = tid; e < P*8; e += NT) kl[e] = kb[e];
  __syncthreads();
  bool act = tid < NTH;
  int pi = tid / PC, pj = tid - pi*PC;
  int i0 = pi*RP, j0 = pj*CP;
  float w[RP][CP];
  if (act){
    #pragma unroll
    for (int r = 0; r < RP; r++){
      float4 v = *(const float4*)(Db + (size_t)(i0+r)*P + j0);
      w[r][0]=v.x; w[r][1]=v.y; w[r][2]=v.z; w[r][3]=v.w;
      int i = i0 + r;
      #pragma unroll
      for (int c = 0; c < CP; c++){
        int j = j0 + c;
        if (i == j) w[r][c] = 0.f;
        else {
          const int* ki = &kl[i*8];
          const int* kj = &kl[j*8];
          bool e = false;
          #pragma unroll
          for (int k = 0; k < 8; k++) e = e || (ki[k] == j) || (kj[k] == i);
          if (!e) w[r][c] = BIGF;
        }
      }
    }
  }
  __syncthreads();
  for (int k = 0; k < P; k++){
    if (act){
      #pragma unroll
      for (int r = 0; r < RP; r++){
        if (i0 + r == k)
          *(float4*)(rowk + j0) = make_float4(w[r][0],w[r][1],w[r][2],w[r][3]);
      }
      #pragma unroll
      for (int c = 0; c < CP; c++){
        if (j0 + c == k){
          #pragma unroll
          for (int r = 0; r < RP; r++) colk[i0+r] = w[r][c];
        }
      }
    }
    __syncthreads();
    if (act){
      float4 rk4 = *(const float4*)(rowk + j0);
      float rk[4] = {rk4.x, rk4.y, rk4.z, rk4.w};
      float ck[RP];
      #pragma unroll
      for (int r = 0; r < RP; r++) ck[r] = colk[i0+r];
      #pragma unroll
      for (int r = 0; r < RP; r++)
        #pragma unroll
        for (int c = 0; c < CP; c++)
          w[r][c] = fminf(w[r][c], ck[r] + rk[c]);
    }
    __syncthreads();
  }
  // window min/max + normalize + write
  float mn = 3.4e38f, mx = -3.4e38f;
  if (act){
    #pragma unroll
    for (int r = 0; r < RP; r++){
      int i = i0 + r;
      if (i >= R0 && i < R0+RR){
        #pragma unroll
        for (int c = 0; c < CP; c++){
          int j = j0 + c;
          if (j >= C0 && j < C0+CC){
            mn = fminf(mn, w[r][c]); mx = fmaxf(mx, w[r][c]);
          }
        }
      }
    }
  }
  rmn[tid] = mn; rmx[tid] = mx;
  __syncthreads();
  for (int o = 512; o > 0; o >>= 1){
    if (tid < o && tid + o < NT){
      rmn[tid] = fminf(rmn[tid], rmn[tid+o]);
      rmx[tid] = fmaxf(rmx[tid], rmx[tid+o]);
    }
    __syncthreads();
  }
  mn = rmn[0]; mx = rmx[0];
  float inv = 1.f/(mx - mn + EPSF);
  if (act){
    #pragma unroll
    for (int r = 0; r < RP; r++){
      int i = i0 + r;
      if (i >= R0 && i < R0+RR){
        #pragma unroll
        for (int c = 0; c < CP; c++){
          int j = j0 + c;
          if (j >= C0 && j < C0+CC)
            outM[((size_t)b*RR + (i-R0))*CC + (j-C0)] = (w[r][c] - mn)*inv;
        }
      }
    }
  }
}

__global__ __launch_bounds__(256) void k_med_hist(const float* __restrict__ x, int N,
                           const float* __restrict__ hs, unsigned* __restrict__ hist){
  __shared__ unsigned lh[1025];
  for (int i = threadIdx.x; i < 1025; i += 256) lh[i] = 0u;
  __syncthreads();
  float lo = hs[0], hi = hs[1];
  float scale = 1024.f/(hi - lo);
  unsigned below = 0;
  int idx = blockIdx.x*256 + threadIdx.x;
  int stride = gridDim.x*256;
  for (int i = idx; i < N; i += stride){
    float v = x[i];
    if (v < lo) below++;
    else if (v < hi){
      int bn = (int)((v - lo)*scale);
      if (bn > 1023) bn = 1023;
      atomicAdd(&lh[bn], 1u);
    }
  }
  for (int o = 32; o > 0; o >>= 1) below += __shfl_down(below, o);
  if ((threadIdx.x & 63) == 0 && below) atomicAdd(&lh[1024], below);
  __syncthreads();
  for (int i = threadIdx.x; i < 1025; i += 256){
    unsigned v = lh[i];
    if (v) atomicAdd(&hist[i], v);
  }
}

// select + zero hist for next use (removes memset launches)
__global__ void k_med_select(float* hs, unsigned* __restrict__ hist, int k){
  if (threadIdx.x == 0){
    float lo = hs[0], hi = hs[1], w = (hi - lo)*(1.f/1024.f);
    unsigned cum = hist[1024];
    int bf = 1023;
    for (int bn = 0; bn < 1024; bn++){
      unsigned h = hist[bn];
      if (cum + h > (unsigned)k){ bf = bn; break; }
      cum += h;
    }
    hs[0] = lo + bf*w; hs[1] = lo + (bf+1)*w;
  }
  __syncthreads();
  for (int i = threadIdx.x; i < 1025; i += 64) hist[i] = 0u;
}

__global__ __launch_bounds__(256) void k_mgap(const float* __restrict__ Mv,
    const float* __restrict__ W1, const float* __restrict__ b1,
    const float* __restrict__ sc, const float* __restrict__ hs,
    float* __restrict__ alpha, float* __restrict__ bet){
  __shared__ float sr[256];
  int b = blockIdx.x;
  float lam1s = 1.f/(1.f + expf(-sc[0]));
  float sig = 0.5f*(hs[0] + hs[1]);
  float inv2s = 1.f/(2.f*sig*sig);
  const float* Mb = Mv + (size_t)b*HW*HW;
  float s = 0.f;
  for (int e = threadIdx.x; e < HW*HW; e += 256){
    float v = Mb[e];
    float f = expf(-v*v*inv2s);
    s += lam1s*f + (1.f - lam1s)*(W1[e]*f + b1[e]);
  }
  sr[threadIdx.x] = s; __syncthreads();
  for (int o = 128; o > 0; o >>= 1){
    if ((int)threadIdx.x < o) sr[threadIdx.x] += sr[threadIdx.x+o];
    __syncthreads();
  }
  if (threadIdx.x == 0){
    float mg = sr[0]*(1.f/(HW*HW));
    alpha[b] = 1.f/(1.f + expf(-(sc[8]*mg + sc[9])));
    bet[b]   = 1.f/(1.f + expf(-(sc[10]*mg + sc[11])));
  }
}

// cast f32 weights -> bf16 (both modality weight tensors, 3x1024x1024 each)
__global__ void k_castw(const float* __restrict__ a, const float* __restrict__ b,
                        short* __restrict__ oa, short* __restrict__ ob){
  int i = (blockIdx.x*256 + threadIdx.x)*4;
  if (i >= 3*C_*C_) return;
  float4 va = *(const float4*)(a + i);
  float4 vb = *(const float4*)(b + i);
  short ra[4] = { f2bf(va.x), f2bf(va.y), f2bf(va.z), f2bf(va.w) };
  short rb[4] = { f2bf(vb.x), f2bf(vb.y), f2bf(vb.z), f2bf(vb.w) };
  *(bhalf*)(oa + i) = *(bhalf*)ra;
  *(bhalf*)(ob + i) = *(bhalf*)rb;
}

// cast n floats -> bf16 (n multiple of 4)
__global__ void k_cast(const float* __restrict__ a, short* __restrict__ oa, int n){
  int i = (blockIdx.x*256 + threadIdx.x)*4;
  if (i >= n) return;
  float4 va = *(const float4*)(a + i);
  short ra[4] = { f2bf(va.x), f2bf(va.y), f2bf(va.z), f2bf(va.w) };
  *(bhalf*)(oa + i) = *(bhalf*)ra;
}

// cast two tensors in one launch
__global__ void k_cast2(const float* __restrict__ a, const float* __restrict__ b,
                        short* __restrict__ oa, short* __restrict__ ob,
                        int n1, int n2){
  int i = (blockIdx.x*256 + threadIdx.x)*4;
  if (i < n1){
    float4 va = *(const float4*)(a + i);
    short ra[4] = { f2bf(va.x), f2bf(va.y), f2bf(va.z), f2bf(va.w) };
    *(bhalf*)(oa + i) = *(bhalf*)ra;
  } else if (i < n1 + n2){
    int k = i - n1;
    float4 vb = *(const float4*)(b + k);
    short rb[4] = { f2bf(vb.x), f2bf(vb.y), f2bf(vb.z), f2bf(vb.w) };
    *(bhalf*)(ob + k) = *(bhalf*)rb;
  }
}

// fused transpose [b][c][t] -> [b][t][c] bf16 for vis & ir, + feat (f32) output
__global__ __launch_bounds__(256) void k_xt2(const float* __restrict__ V,
    const float* __restrict__ I, const float* __restrict__ alpha,
    const float* __restrict__ bet, short* __restrict__ XtV,
    short* __restrict__ XtI, float* __restrict__ feat){
  __shared__ float tv[32][33], ti[32][33];
  int c0 = blockIdx.x*32, t0 = blockIdx.y*32, b = blockIdx.z;
  int j = threadIdx.x & 31, i0 = threadIdx.x >> 5;
  for (int i = i0; i < 32; i += 8){
    int t = t0 + j;
    float a = 0.f, c = 0.f;
    if (t < HW){
      a = V[((size_t)b*C_ + c0+i)*HW + t];
      c = I[((size_t)b*C_ + c0+i)*HW + t];
    }
    tv[i][j] = a; ti[i][j] = c;
  }
  __syncthreads();
  float al = alpha[b], bt = bet[b];
  for (int i = i0; i < 32; i += 8){
    int t = t0 + i;
    if (t < HW){
      float fv = tv[j][i], fi = ti[j][i];
      size_t off = ((size_t)b*HW + t)*C_ + c0 + j;
      XtV[off] = f2bf(fv);
      XtI[off] = f2bf(fi);
      feat[off] = al*fv + bt*fi;
    }
  }
}

// transpose lan [b][c][20] f32 -> lanT [(b*20+t)][c] bf16
__global__ __launch_bounds__(256) void k_lanT(const float* __restrict__ lan,
                                              short* __restrict__ lanT){
  __shared__ float tile[32][21];
  int c0 = blockIdx.x*32, b = blockIdx.y;
  for (int e = threadIdx.x; e < 32*MT_; e += 256){
    int c = e / MT_, t = e - c*MT_;
    tile[c][t] = lan[((size_t)b*C_ + c0+c)*MT_ + t];
  }
  __syncthreads();
  for (int e = threadIdx.x; e < 32*MT_; e += 256){
    int t = e >> 5, c = e & 31;
    lanT[((size_t)(b*MT_ + t))*C_ + c0 + c] = f2bf(tile[c][t]);
  }
}

// Direct global->register MFMA conv1x1 + IN + ReLU + alpha/beta combine.
// m-tile 128 (round-10 config, measured best 425us, FROZEN).
__global__ __launch_bounds__(256) void k_convqkv_mfma(
    const short* __restrict__ XtV, const short* __restrict__ XtI,
    const short* __restrict__ WV,  const short* __restrict__ WI,
    const float* __restrict__ vg, const float* __restrict__ vbe,
    const float* __restrict__ ig, const float* __restrict__ ibe,
    const float* __restrict__ alpha, const float* __restrict__ bet,
    float* __restrict__ out){
  int m0 = blockIdx.x*128;
  int wsel = blockIdx.y;
  int b = blockIdx.z;
  int tid = threadIdx.x;
  int lane = tid & 63, w = tid >> 6;
  int lg = lane >> 4, lr = lane & 15;
  f32x4 acc[7][2][2];
  #pragma unroll
  for (int tf = 0; tf < 7; tf++)
    #pragma unroll
    for (int mf = 0; mf < 2; mf++)
      #pragma unroll
      for (int md = 0; md < 2; md++)
        acc[tf][mf][md] = (f32x4){0.f,0.f,0.f,0.f};
  const short* xvp = XtV + (size_t)b*HW*C_ + (size_t)lr*C_ + lg*8;
  const short* xip = XtI + (size_t)b*HW*C_ + (size_t)lr*C_ + lg*8;
  const short* wvp = WV + (size_t)wsel*C_*C_ + (size_t)(m0 + w*32 + lr)*C_ + lg*8;
  const short* wip = WI + (size_t)wsel*C_*C_ + (size_t)(m0 + w*32 + lr)*C_ + lg*8;
  const bfrag zf = {0,0,0,0,0,0,0,0};
  for (int k0 = 0; k0 < C_; k0 += 32){
    bfrag bw0v = *(const bfrag*)(wvp + k0);
    bfrag bw1v = *(const bfrag*)(wvp + (size_t)16*C_ + k0);
    bfrag bw0i = *(const bfrag*)(wip + k0);
    bfrag bw1i = *(const bfrag*)(wip + (size_t)16*C_ + k0);
    #pragma unroll
    for (int tf = 0; tf < 7; tf++){
      bfrag axv = zf, axi = zf;
      if (tf*16 + lr < HW){
        axv = *(const bfrag*)(xvp + (size_t)tf*16*C_ + k0);
        axi = *(const bfrag*)(xip + (size_t)tf*16*C_ + k0);
      }
      acc[tf][0][0] = MFMA_B16(axv, bw0v, acc[tf][0][0]);
      acc[tf][1][0] = MFMA_B16(axv, bw1v, acc[tf][1][0]);
      acc[tf][0][1] = MFMA_B16(axi, bw0i, acc[tf][0][1]);
      acc[tf][1][1] = MFMA_B16(axi, bw1i, acc[tf][1][1]);
    }
  }
  float al = alpha[b], bt = bet[b];
  float* ob = out + ((size_t)(wsel*B_ + b))*HW*C_;
  #pragma unroll
  for (int mf = 0; mf < 2; mf++){
    int m = m0 + w*32 + mf*16 + lr;
    float s1v=0.f,s2v=0.f,s1i=0.f,s2i=0.f;
    #pragma unroll
    for (int tf = 0; tf < 7; tf++){
      #pragma unroll
      for (int r = 0; r < 4; r++){
        int t = tf*16 + lg*4 + r;
        if (t < HW){
          float yv = acc[tf][mf][0][r], yi = acc[tf][mf][1][r];
          s1v += yv; s2v += yv*yv; s1i += yi; s2i += yi*yi;
        }
      }
    }
    s1v += __shfl_xor(s1v,16); s1v += __shfl_xor(s1v,32);
    s2v += __shfl_xor(s2v,16); s2v += __shfl_xor(s2v,32);
    s1i += __shfl_xor(s1i,16); s1i += __shfl_xor(s1i,32);
    s2i += __shfl_xor(s2i,16); s2i += __shfl_xor(s2i,32);
    float muv = s1v*0.01f, varv = s2v*0.01f - muv*muv;
    float mui = s1i*0.01f, vari = s2i*0.01f - mui*mui;
    float scv = vg[wsel*C_+m]/sqrtf(varv+1e-5f);
    float shv = vbe[wsel*C_+m] - muv*scv;
    float sci = ig[wsel*C_+m]/sqrtf(vari+1e-5f);
    float shi = ibe[wsel*C_+m] - mui*sci;
    #pragma unroll
    for (int tf = 0; tf < 7; tf++){
      #pragma unroll
      for (int r = 0; r < 4; r++){
        int t = tf*16 + lg*4 + r;
        if (t < HW){
          float yv = fmaxf(acc[tf][mf][0][r]*scv + shv, 0.f);
          float yi = fmaxf(acc[tf][mf][1][r]*sci + shi, 0.f);
          ob[(size_t)t*C_ + m] = al*yv + bt*yi;
        }
      }
    }
  }
}

// Packed-row GEMM: out[row][n] = sum_c X[row][c]*W16[n][c] + bias[n], 1280 rows.
__global__ __launch_bounds__(256) void k_tokproj_mfma(
    const float* __restrict__ X, const short* __restrict__ W16,
    const float* __restrict__ bias, float* __restrict__ out){
  constexpr int NROW = B_*MT_;
  int n0 = blockIdx.x*128;
  int t0 = blockIdx.y*112;
  int tid = threadIdx.x;
  int lane = tid & 63, w = tid >> 6;
  int lg = lane >> 4, lr = lane & 15;
  f32x4 acc[7][2];
  #pragma unroll
  for (int tf = 0; tf < 7; tf++)
    #pragma unroll
    for (int mf = 0; mf < 2; mf++)
      acc[tf][mf] = (f32x4){0.f,0.f,0.f,0.f};
  const short* wp = W16 + (size_t)(n0 + w*32 + lr)*C_ + lg*8;
  const bfrag zf = {0,0,0,0,0,0,0,0};
  for (int k0 = 0; k0 < C_; k0 += 32){
    bfrag bw0 = *(const bfrag*)(wp + k0);
    bfrag bw1 = *(const bfrag*)(wp + (size_t)16*C_ + k0);
    #pragma unroll
    for (int tf = 0; tf < 7; tf++){
      bfrag ax = zf;
      int row = t0 + tf*16 + lr;
      if (row < NROW){
        const float* ap = X + (size_t)row*C_ + k0 + lg*8;
        float4 u = *(const float4*)ap;
        float4 v = *(const float4*)(ap + 4);
        ax[0]=f2bf(u.x); ax[1]=f2bf(u.y); ax[2]=f2bf(u.z); ax[3]=f2bf(u.w);
        ax[4]=f2bf(v.x); ax[5]=f2bf(v.y); ax[6]=f2bf(v.z); ax[7]=f2bf(v.w);
      }
      acc[tf][0] = MFMA_B16(ax, bw0, acc[tf][0]);
      acc[tf][1] = MFMA_B16(ax, bw1, acc[tf][1]);
    }
  }
  #pragma unroll
  for (int mf = 0; mf < 2; mf++){
    int n = n0 + w*32 + mf*16 + lr;
    float bv = bias[n];
    #pragma unroll
    for (int tf = 0; tf < 7; tf++){
      #pragma unroll
      for (int r = 0; r < 4; r++){
        int row = t0 + tf*16 + lg*4 + r;
        if (row < NROW) out[(size_t)row*C_ + n] = acc[tf][mf][r] + bv;
      }
    }
  }
}

#define TPAD 36
// MFMA final conv: out[b][n][t] = sum_m W[n][m]*NVb[b][t][m] + bias[n]
__global__ __launch_bounds__(256) void k_convout_mfma(
    const short* __restrict__ NVb, const short* __restrict__ Wb,
    const float* __restrict__ bias, float* __restrict__ out){
  __shared__ short xs[112*TPAD];
  __shared__ short wsm[128*TPAD];
  int n0 = blockIdx.x*128, b = blockIdx.y;
  int tid = threadIdx.x;
  int lane = tid & 63, w = tid >> 6;
  int lg = lane >> 4, lr = lane & 15;
  for (int e = tid; e < 12*TPAD; e += 256) xs[100*TPAD + e] = 0;
  f32x4 acc[7][2];
  #pragma unroll
  for (int tf = 0; tf < 7; tf++)
    #pragma unroll
    for (int nf = 0; nf < 2; nf++)
      acc[tf][nf] = (f32x4){0.f,0.f,0.f,0.f};
  const short* xg = NVb + (size_t)b*HW*C_;
  const short* wg = Wb + (size_t)n0*C_;
  int rr0 = tid >> 3, kk = (tid & 7)*4;
  for (int k0 = 0; k0 < C_; k0 += 32){
    __syncthreads();
    for (int rr = rr0; rr < HW; rr += 32)
      *(uint2*)&xs[rr*TPAD + kk] = *(const uint2*)(xg + (size_t)rr*C_ + k0 + kk);
    for (int rr = rr0; rr < 128; rr += 32)
      *(uint2*)&wsm[rr*TPAD + kk] = *(const uint2*)(wg + (size_t)rr*C_ + k0 + kk);
    __syncthreads();
    const short* pw0 = &wsm[(w*32 + lr)*TPAD + lg*4];
    const short* pw1 = &wsm[(w*32 + 16 + lr)*TPAD + lg*4];
    bhalf l0, h0;
    l0 = *(const bhalf*)pw0; h0 = *(const bhalf*)(pw0 + 16);
    bfrag aw0 = {l0[0],l0[1],l0[2],l0[3],h0[0],h0[1],h0[2],h0[3]};
    l0 = *(const bhalf*)pw1; h0 = *(const bhalf*)(pw1 + 16);
    bfrag aw1 = {l0[0],l0[1],l0[2],l0[3],h0[0],h0[1],h0[2],h0[3]};
    #pragma unroll
    for (int tf = 0; tf < 7; tf++){
      const short* pb = &xs[(tf*16 + lr)*TPAD + lg*4];
      bhalf bl_ = *(const bhalf*)pb, bh_ = *(const bhalf*)(pb + 16);
      bfrag bx = {bl_[0],bl_[1],bl_[2],bl_[3],bh_[0],bh_[1],bh_[2],bh_[3]};
      acc[tf][0] = MFMA_B16(aw0, bx, acc[tf][0]);
      acc[tf][1] = MFMA_B16(aw1, bx, acc[tf][1]);
    }
  }
  float* ob = out + (size_t)b*C_*HW;
  #pragma unroll
  for (int nf = 0; nf < 2; nf++){
    #pragma unroll
    for (int r = 0; r < 4; r++){
      int n = n0 + w*32 + nf*16 + lg*4 + r;
      float bv = bias[n];
      #pragma unroll
      for (int tf = 0; tf < 7; tf++){
        int t = tf*16 + lr;
        if (t < HW) ob[(size_t)n*HW + t] = acc[tf][nf][r] + bv;
      }
    }
  }
}

// MFMA text projections over packed token rows (row = b*20+t, 1280 rows).
__global__ __launch_bounds__(256) void k_textproj_mfma(
    const short* __restrict__ lanT, const short* __restrict__ Wt,
    const float* __restrict__ tb, float* __restrict__ QKVt, float* __restrict__ lanML){
  constexpr int NROW = B_*MT_;
  __shared__ short xs[112*TPAD];
  __shared__ short wsm[128*TPAD];
  int m0 = blockIdx.x*128;
  int t0 = blockIdx.y*112;
  int wsel = blockIdx.z;
  int tid = threadIdx.x;
  int lane = tid & 63, w = tid >> 6;
  int lg = lane >> 4, lr = lane & 15;
  f32x4 acc[7][2];
  #pragma unroll
  for (int tf = 0; tf < 7; tf++)
    #pragma unroll
    for (int mf = 0; mf < 2; mf++)
      acc[tf][mf] = (f32x4){0.f,0.f,0.f,0.f};
  const short* wg = Wt + (size_t)wsel*C_*C_ + (size_t)m0*C_;
  int rr0 = tid >> 3, kk = (tid & 7)*4;
  for (int k0 = 0; k0 < C_; k0 += 32){
    __syncthreads();
    for (int rr = rr0; rr < 112; rr += 32){
      int row = t0 + rr;
      uint2 v = make_uint2(0u, 0u);
      if (row < NROW) v = *(const uint2*)(lanT + (size_t)row*C_ + k0 + kk);
      *(uint2*)&xs[rr*TPAD + kk] = v;
    }
    for (int rr = rr0; rr < 128; rr += 32)
      *(uint2*)&wsm[rr*TPAD + kk] = *(const uint2*)(wg + (size_t)rr*C_ + k0 + kk);
    __syncthreads();
    const short* pw0 = &wsm[(w*32 + lr)*TPAD + lg*4];
    const short* pw1 = &wsm[(w*32 + 16 + lr)*TPAD + lg*4];
    bhalf l0, h0;
    l0 = *(const bhalf*)pw0; h0 = *(const bhalf*)(pw0 + 16);
    bfrag bw0 = {l0[0],l0[1],l0[2],l0[3],h0[0],h0[1],h0[2],h0[3]};
    l0 = *(const bhalf*)pw1; h0 = *(const bhalf*)(pw1 + 16);
    bfrag bw1 = {l0[0],l0[1],l0[2],l0[3],h0[0],h0[1],h0[2],h0[3]};
    #pragma unroll
    for (int tf = 0; tf < 7; tf++){
      const short* pa = &xs[(tf*16 + lr)*TPAD + lg*4];
      bhalf al_ = *(const bhalf*)pa, ah_ = *(const bhalf*)(pa + 16);
      bfrag ax = {al_[0],al_[1],al_[2],al_[3],ah_[0],ah_[1],ah_[2],ah_[3]};
      acc[tf][0] = MFMA_B16(ax, bw0, acc[tf][0]);
      acc[tf][1] = MFMA_B16(ax, bw1, acc[tf][1]);
    }
  }
  bool isml = (wsel == 3);
  #pragma unroll
  for (int mf = 0; mf < 2; mf++){
    int m = m0 + w*32 + mf*16 + lr;
    float bv = isml ? 0.f : tb[wsel*C_ + m];
    #pragma unroll
    for (int tf = 0; tf < 7; tf++){
      #pragma unroll
      for (int r = 0; r < 4; r++){
        int row = t0 + tf*16 + lg*4 + r;
        if (row < NROW){
          float v = acc[tf][mf][r] + bv;
          if (!isml) v = fmaxf(v, 0.f);
          if (isml) lanML[(size_t)row*C_ + m] = v;
          else      QKVt[((size_t)wsel*NROW + row)*C_ + m] = v;
        }
      }
    }
  }
}

// fused: Mfix = exp(-Mt^2/(2 sigma^2)); Ppre[(b*HW+i)*MT+j] from Mfix
__global__ void k_mfixppre(const float* __restrict__ Mt, const float* __restrict__ hs2,
                           const float* __restrict__ W2, const float* __restrict__ b2,
                           const float* __restrict__ sc,
                           float* __restrict__ Mfix, float* __restrict__ Ppre){
  int idx = blockIdx.x*256 + threadIdx.x;
  if (idx >= B_*MT_*HW) return;
  int i = idx % HW;
  int j = (idx/HW) % MT_;
  int b = idx/(MT_*HW);
  float sig = 0.5f*(hs2[0] + hs2[1]);
  float v = Mt[idx];
  float f = expf(-v*v/(2.f*sig*sig));
  Mfix[idx] = f;
  float lam2s = 1.f/(1.f + expf(-sc[1]));
  Ppre[((size_t)b*HW + i)*MT_ + j] = lam2s*f + (1.f - lam2s)*(W2[i*MT_ + j]*f + b2[i*MT_ + j]);
}

__global__ __launch_bounds__(256) void k_sm20(const float* __restrict__ Ppre, float* __restrict__ Pi2t){
  int row = blockIdx.x*8 + (threadIdx.x >> 5);
  int lane = threadIdx.x & 31;
  if (row >= B_*HW) return;
  float v = (lane < MT_) ? Ppre[(size_t)row*MT_ + lane]*(1.f/SQC) : -3.4e38f;
  float m = v;
  for (int o = 16; o > 0; o >>= 1) m = fmaxf(m, __shfl_xor(m, o, 32));
  float e = (lane < MT_) ? expf(v - m) : 0.f;
  float s = e;
  for (int o = 16; o > 0; o >>= 1) s += __shfl_xor(s, o, 32);
  if (lane < MT_) Pi2t[(size_t)row*MT_ + lane] = e/s;
}

__global__ __launch_bounds__(128) void k_smT(const float* __restrict__ Ppre, float* __restrict__ Pt2i){
  __shared__ float sm[128], ss[128];
  int bj = blockIdx.x; int b = bj/MT_, j = bj % MT_;
  int i = threadIdx.x;
  float v = (i < HW) ? Ppre[((size_t)b*HW + i)*MT_ + j]*(1.f/SQC) : -3.4e38f;
  sm[i] = v; __syncthreads();
  for (int o = 64; o > 0; o >>= 1){
    if (i < o) sm[i] = fmaxf(sm[i], sm[i+o]);
    __syncthreads();
  }
  float m = sm[0];
  float e = (i < HW) ? expf(v - m) : 0.f;
  ss[i] = e; __syncthreads();
  for (int o = 64; o > 0; o >>= 1){
    if (i < o) ss[i] += ss[i+o];
    __syncthreads();
  }
  if (i < HW) Pt2i[((size_t)b*MT_ + j)*HW + i] = e/ss[0];
}

// merged mlearn_t2i + t2 (same math/order as the two originals; one launch)
__global__ __launch_bounds__(256) void k_mlearn2(const float* __restrict__ Pi2t,
    const float* __restrict__ Pt2i, const float* __restrict__ lanML,
    const float* __restrict__ mlb, const float* __restrict__ feat,
    float* __restrict__ outMl, float* __restrict__ T2o){
  __shared__ float sP[HW][MT_];
  __shared__ float sQ[MT_][HW];
  int b = blockIdx.y; int m = blockIdx.x*256 + threadIdx.x;
  for (int e = threadIdx.x; e < HW*MT_; e += 256){
    sP[e/MT_][e%MT_] = Pi2t[(size_t)b*HW*MT_ + e];
    sQ[e/HW][e%HW]   = Pt2i[(size_t)b*MT_*HW + e];
  }
  __syncthreads();
  float vL[MT_];
  #pragma unroll
  for (int j = 0; j < MT_; j++) vL[j] = lanML[((size_t)b*MT_ + j)*C_ + m];
  float accT[MT_];
  #pragma unroll
  for (int j = 0; j < MT_; j++) accT[j] = 0.f;
  float bb = mlb[m];
  for (int i = 0; i < HW; i++){
    float f = feat[((size_t)b*HW + i)*C_ + m];
    float a = bb;
    #pragma unroll
    for (int j = 0; j < MT_; j++){
      a += sP[i][j]*vL[j];
      accT[j] += sQ[j][i]*f;
    }
    outMl[((size_t)b*HW + i)*C_ + m] = a;
  }
  #pragma unroll
  for (int j = 0; j < MT_; j++) T2o[((size_t)b*MT_ + j)*C_ + m] = accT[j];
}

// W4Ml[b][q][c] = sum_p W4[q][p] * Ml[b][p][c]   (associativity restructure)
__global__ __launch_bounds__(256) void k_w4ml(const float* __restrict__ W4,
    const float* __restrict__ Ml, float* __restrict__ out){
  __shared__ float sW[MT_][HW];
  int b = blockIdx.y; int m = blockIdx.x*256 + threadIdx.x;
  for (int e = threadIdx.x; e < MT_*HW; e += 256) sW[e/HW][e%HW] = W4[e];
  __syncthreads();
  float acc[MT_];
  #pragma unroll
  for (int j = 0; j < MT_; j++) acc[j] = 0.f;
  for (int p = 0; p < HW; p++){
    float f = Ml[((size_t)b*HW + p)*C_ + m];
    #pragma unroll
    for (int j = 0; j < MT_; j++) acc[j] += sW[j][p]*f;
  }
  #pragma unroll
  for (int j = 0; j < MT_; j++) out[((size_t)b*MT_ + j)*C_ + m] = acc[j];
}

__global__ __launch_bounds__(256) void k_abt(const float* __restrict__ X,
    const float* __restrict__ Y, float* __restrict__ out, int I, int Jd){
  __shared__ float Xs[16][33], Ys[64][33];
  int i0 = blockIdx.x*16, j0 = blockIdx.y*64, b = blockIdx.z;
  int jl = threadIdx.x & 63, ig = threadIdx.x >> 6;
  float acc[4] = {0.f,0.f,0.f,0.f};
  const float* Xb = X + (size_t)b*I*C_;
  const float* Yb = Y + (size_t)b*Jd*C_;
  for (int c0 = 0; c0 < C_; c0 += 32){
    for (int e = threadIdx.x; e < 512; e += 256){
      int r = e >> 5, cc = e & 31;
      Xs[r][cc] = (i0+r < I) ? Xb[(size_t)(i0+r)*C_ + c0+cc] : 0.f;
    }
    for (int e = threadIdx.x; e < 2048; e += 256){
      int r = e >> 5, cc = e & 31;
      Ys[r][cc] = (j0+r < Jd) ? Yb[(size_t)(j0+r)*C_ + c0+cc] : 0.f;
    }
    __syncthreads();
    for (int kk = 0; kk < 32; kk++){
      float y = Ys[jl][kk];
      #pragma unroll
      for (int k = 0; k < 4; k++) acc[k] += Xs[ig*4+k][kk]*y;
    }
    __syncthreads();
  }
  #pragma unroll
  for (int k = 0; k < 4; k++){
    int i = i0 + ig*4 + k, j = j0 + jl;
    if (i < I && j < Jd) out[((size_t)b*I + i)*Jd + j] = acc[k];
  }
}

// fused double-B k_abt: out1 = X@Y1^T, out2 = X@Y2^T (shared A read).
__global__ __launch_bounds__(256) void k_abt2(const float* __restrict__ X,
    const float* __restrict__ Y1, const float* __restrict__ Y2,
    float* __restrict__ out1, float* __restrict__ out2, int I, int Jd){
  __shared__ float Xs[16][33], Y1s[64][33], Y2s[64][33];
  int i0 = blockIdx.x*16, j0 = blockIdx.y*64, b = blockIdx.z;
  int jl = threadIdx.x & 63, ig = threadIdx.x >> 6;
  float acc1[4] = {0.f,0.f,0.f,0.f};
  float acc2[4] = {0.f,0.f,0.f,0.f};
  const float* Xb  = X  + (size_t)b*I*C_;
  const float* Y1b = Y1 + (size_t)b*Jd*C_;
  const float* Y2b = Y2 + (size_t)b*Jd*C_;
  for (int c0 = 0; c0 < C_; c0 += 32){
    for (int e = threadIdx.x; e < 512; e += 256){
      int r = e >> 5, cc = e & 31;
      Xs[r][cc] = (i0+r < I) ? Xb[(size_t)(i0+r)*C_ + c0+cc] : 0.f;
    }
    for (int e = threadIdx.x; e < 2048; e += 256){
      int r = e >> 5, cc = e & 31;
      bool ok = (j0+r < Jd);
      Y1s[r][cc] = ok ? Y1b[(size_t)(j0+r)*C_ + c0+cc] : 0.f;
      Y2s[r][cc] = ok ? Y2b[(size_t)(j0+r)*C_ + c0+cc] : 0.f;
    }
    __syncthreads();
    for (int kk = 0; kk < 32; kk++){
      float y1 = Y1s[jl][kk], y2 = Y2s[jl][kk];
      #pragma unroll
      for (int k = 0; k < 4; k++){
        float x = Xs[ig*4+k][kk];
        acc1[k] += x*y1;
        acc2[k] += x*y2;
      }
    }
    __syncthreads();
  }
  #pragma unroll
  for (int k = 0; k < 4; k++){
    int i = i0 + ig*4 + k, j = j0 + jl;
    if (i < I && j < Jd){
      out1[((size_t)b*I + i)*Jd + j] = acc1[k];
      out2[((size_t)b*I + i)*Jd + j] = acc2[k];
    }
  }
}

// attA (+fused lossA): S3n precomputed [B,MT,HW] -> pure elementwise combine.
__global__ __launch_bounds__(128) void k_attA(const float* __restrict__ S1,
    const float* __restrict__ S2, const float* __restrict__ S3n,
    const float* __restrict__ sc, const float* __restrict__ Mfix,
    float* __restrict__ Av, float* __restrict__ pa){
  __shared__ float red[128];
  int bq = blockIdx.x;
  int j = threadIdx.x;
  float a1 = sc[2], be1 = sc[3];
  float v = -3.4e38f;
  if (j < HW){
    size_t off = (size_t)bq*HW + j;
    v = (S1[off] + a1*S2[off] + be1*S3n[off])*(1.f/SQC);
  }
  red[j] = v; __syncthreads();
  for (int o = 64; o > 0; o >>= 1){
    if (j < o) red[j] = fmaxf(red[j], red[j+o]);
    __syncthreads();
  }
  float m = red[0]; __syncthreads();
  float e = (j < HW) ? expf(v - m) : 0.f;
  red[j] = e; __syncthreads();
  for (int o = 64; o > 0; o >>= 1){
    if (j < o) red[j] += red[j+o];
    __syncthreads();
  }
  float av = (j < HW) ? e/red[0] : 0.f;
  if (j < HW) Av[(size_t)bq*HW + j] = av;
  __syncthreads();
  // ---- loss part ----
  float vm = (j < HW) ? Mfix[(size_t)bq*HW + j]*(1.f/SQC) : -3.4e38f;
  red[j] = vm; __syncthreads();
  for (int o = 64; o > 0; o >>= 1){
    if (j < o) red[j] = fmaxf(red[j], red[j+o]);
    __syncthreads();
  }
  float mm = red[0]; __syncthreads();
  float em = (j < HW) ? expf(vm - mm) : 0.f;
  red[j] = em; __syncthreads();
  for (int o = 64; o > 0; o >>= 1){
    if (j < o) red[j] += red[j+o];
    __syncthreads();
  }
  float fa = (j < HW) ? em/red[0] : 0.f;
  __syncthreads();
  float p[5] = { fabsf(av - fa), av, av*av, fa, fa*fa };
  for (int s = 0; s < 5; s++){
    red[j] = p[s]; __syncthreads();
    for (int o = 64; o > 0; o >>= 1){
      if (j < o) red[j] += red[j+o];
      __syncthreads();
    }
    if (j == 0) pa[bq*5 + s] = red[0];
    __syncthreads();
  }
}

// attB (+fused lossB)
__global__ __launch_bounds__(256) void k_attB(const float* __restrict__ S4a,
    const float* __restrict__ S4b, const float* __restrict__ S5,
    const float* __restrict__ W5, const float* __restrict__ sc,
    const float* __restrict__ Mfix, float* __restrict__ Bv, float* __restrict__ pb){
  __shared__ float red[8];
  int row = blockIdx.x*8 + (threadIdx.x >> 5);
  int lane = threadIdx.x & 31;
  int b = row/HW, i = row % HW;
  float a2 = sc[5], be2 = sc[6];
  float v = -3.4e38f;
  if (lane < MT_){
    float s5 = 0.f;
    const float* S5b = S5 + (size_t)b*MT_*MT_ + lane;
    const float* w5 = W5 + (size_t)i*MT_;
    #pragma unroll
    for (int p = 0; p < MT_; p++) s5 += w5[p]*S5b[p*MT_];
    size_t off = (size_t)row*MT_ + lane;
    v = (S4a[off] + a2*S4b[off] + be2*s5)*(1.f/SQC);
  }
  float m = v;
  for (int o = 16; o > 0; o >>= 1) m = fmaxf(m, __shfl_xor(m, o, 32));
  float e = (lane < MT_) ? expf(v - m) : 0.f;
  float s = e;
  for (int o = 16; o > 0; o >>= 1) s += __shfl_xor(s, o, 32);
  float bv = (lane < MT_) ? e/s : 0.f;
  if (lane < MT_) Bv[(size_t)row*MT_ + lane] = bv;
  // ---- loss part ----
  float vm = (lane < MT_) ? Mfix[((size_t)b*MT_ + lane)*HW + i]*(1.f/SQC) : -3.4e38f;
  float mm = vm;
  for (int o = 16; o > 0; o >>= 1) mm = fmaxf(mm, __shfl_xor(mm, o, 32));
  float em = (lane < MT_) ? expf(vm - mm) : 0.f;
  float sm = em;
  for (int o = 16; o > 0; o >>= 1) sm += __shfl_xor(sm, o, 32);
  float fb = (lane < MT_) ? em/sm : 0.f;
  float p[5] = { fabsf(bv - fb), bv, bv*bv, fb, fb*fb };
  for (int s5 = 0; s5 < 5; s5++){
    float x = p[s5];
    for (int o = 16; o > 0; o >>= 1) x += __shfl_xor(x, o, 32);
    if (lane == 0) red[threadIdx.x >> 5] = x;
    __syncthreads();
    if (threadIdx.x == 0){
      float t = 0.f;
      for (int g = 0; g < 8; g++) t += red[g];
      pb[blockIdx.x*5 + s5] = t;
    }
    __syncthreads();
  }
}

__global__ __launch_bounds__(256) void k_nl(const float* __restrict__ Av,
    const float* __restrict__ Pt2i, const float* __restrict__ Vf,
    const float* __restrict__ sc, float* __restrict__ NL){
  __shared__ float sA[MT_][HW];
  int b = blockIdx.y; int m = blockIdx.x*256 + threadIdx.x;
  float g1 = sc[4];
  for (int e = threadIdx.x; e < MT_*HW; e += 256)
    sA[e/HW][e%HW] = Av[(size_t)b*MT_*HW + e] + g1*Pt2i[(size_t)b*MT_*HW + e];
  __syncthreads();
  float acc[MT_];
  #pragma unroll
  for (int q = 0; q < MT_; q++) acc[q] = 0.f;
  for (int k = 0; k < HW; k++){
    float v = Vf[((size_t)b*HW + k)*C_ + m];
    #pragma unroll
    for (int q = 0; q < MT_; q++) acc[q] += sA[q][k]*v;
  }
  #pragma unroll
  for (int q = 0; q < MT_; q++) NL[((size_t)b*MT_ + q)*C_ + m] = acc[q];
}

// NV in bf16 (sole consumer is k_convout_mfma)
__global__ __launch_bounds__(256) void k_nv(const float* __restrict__ Bv,
    const float* __restrict__ Pi2t, const float* __restrict__ Vt,
    const float* __restrict__ sc, short* __restrict__ NVb){
  __shared__ float sB[HW][MT_];
  int b = blockIdx.y; int m = blockIdx.x*256 + threadIdx.x;
  float g2 = sc[7];
  for (int e = threadIdx.x; e < HW*MT_; e += 256)
    sB[e/MT_][e%MT_] = Bv[(size_t)b*HW*MT_ + e] + g2*Pi2t[(size_t)b*HW*MT_ + e];
  __syncthreads();
  float vT[MT_];
  #pragma unroll
  for (int j = 0; j < MT_; j++) vT[j] = Vt[((size_t)b*MT_ + j)*C_ + m];
  for (int i = 0; i < HW; i++){
    float a = 0.f;
    #pragma unroll
    for (int j = 0; j < MT_; j++) a += sB[i][j]*vT[j];
    NVb[((size_t)b*HW + i)*C_ + m] = f2bf(a);
  }
}

__global__ __launch_bounds__(256) void k_loss_final(const float* __restrict__ pa,
    const float* __restrict__ pb, float* __restrict__ outloss){
  __shared__ float red[256];
  float s[5] = {0,0,0,0,0}, t[5] = {0,0,0,0,0};
  for (int r = threadIdx.x; r < 1280; r += 256)
    for (int k = 0; k < 5; k++) s[k] += pa[r*5 + k];
  for (int r = threadIdx.x; r < 800; r += 256)
    for (int k = 0; k < 5; k++) t[k] += pb[r*5 + k];
  float res[10];
  for (int k = 0; k < 5; k++){
    red[threadIdx.x] = s[k]; __syncthreads();
    for (int o = 128; o > 0; o >>= 1){
      if ((int)threadIdx.x < o) red[threadIdx.x] += red[threadIdx.x+o];
      __syncthreads();
    }
    res[k] = red[0]; __syncthreads();
  }
  for (int k = 0; k < 5; k++){
    red[threadIdx.x] = t[k]; __syncthreads();
    for (int o = 128; o > 0; o >>= 1){
      if ((int)threadIdx.x < o) red[threadIdx.x] += red[threadIdx.x+o];
      __syncthreads();
    }
    res[5+k] = red[0]; __syncthreads();
  }
  if (threadIdx.x == 0){
    const float n = 128000.f;
    float l1 = res[0]/n + res[5]/n;
    float varAv = (res[2] - res[1]*res[1]/n)/(n - 1.f);
    float varfA = (res[4] - res[3]*res[3]/n)/(n - 1.f);
    float varBv = (res[7] - res[6]*res[6]/n)/(n - 1.f);
    float varfB = (res[9] - res[8]*res[8]/n)/(n - 1.f);
    float l2 = -fabsf(varAv - varfA) - fabsf(varBv - varfB);
    outloss[0] = (l1 + 100.f*l2)*1000.f;
  }
}

// ---------------- launcher ----------------
extern "C" void kernel_launch(void* const* d_in, const int* in_sizes, int n_in,
                              void* d_out, int out_size, void* d_ws, size_t ws_size,
                              hipStream_t stream){
  const float* ir     = (const float*)d_in[0];
  const float* vis    = (const float*)d_in[1];
  const float* lan    = (const float*)d_in[2];
  const float* vis_w  = (const float*)d_in[3];
  const float* vis_g  = (const float*)d_in[5];
  const float* vis_be = (const float*)d_in[6];
  const float* ir_w   = (const float*)d_in[7];
  const float* ir_g   = (const float*)d_in[9];
  const float* ir_be  = (const float*)d_in[10];
  const float* t_w    = (const float*)d_in[11];
  const float* t_b    = (const float*)d_in[12];
  const float* vout_w = (const float*)d_in[13];
  const float* vout_b = (const float*)d_in[14];
  const float* tout_w = (const float*)d_in[15];
  const float* tout_b = (const float*)d_in[16];
  const float* W1     = (const float*)d_in[17];
  const float* b1     = (const float*)d_in[18];
  const float* W2     = (const float*)d_in[19];
  const float* b2     = (const float*)d_in[20];
  const float* W4     = (const float*)d_in[21];
  const float* W5     = (const float*)d_in[22];
  const float* ml_w   = (const float*)d_in[23];
  const float* ml_b   = (const float*)d_in[24];
  const float* ml2_w  = (const float*)d_in[25];
  const float* ml2_b  = (const float*)d_in[26];
  const float* sc     = (const float*)d_in[27];

  float* ws = (float*)d_ws;
  float* J     = ws + F_J;
  float* Dm    = ws + F_D;
  float* sqb   = ws + F_SQ;
  int*   knn   = (int*)(ws + F_KNN);
  float* Mv    = ws + F_MV;
  float* Mt    = ws + F_MT;
  float* Mfix  = ws + F_MFIX;
  float* QKVf  = ws + F_QKVF;
  float* QKVt  = ws + F_QKVT;
  float* feat  = ws + F_FEAT;
  float* lanML = ws + F_LANML;
  float* T2b   = ws + F_T2;
  float* Mi2tL = ws + F_MI2TL;
  float* S1    = ws + F_S1;
  float* S2    = ws + F_S2;
  float* S4a   = ws + F_S4A;
  float* S4b   = ws + F_S4B;
  float* S5    = ws + F_S5;
  float* Av    = ws + F_AV;
  float* Bv    = ws + F_BV;
  float* NL    = ws + F_NL;
  float* alpha = ws + F_AL;
  float* bet   = ws + F_BE;
  float* hs    = ws + F_HS;
  unsigned* hist = (unsigned*)(ws + F_HIST);
  float* pa    = ws + F_PA;
  float* pb    = ws + F_PB;
  // overlays
  float* MlT2I = ws + F_J;
  float* S3n   = ws + F_D;
  float* W4Ml  = ws + F_T2;          // T2b dead after tokproj
  float* Pi2t  = ws + F_MV;
  float* Pt2i  = ws + F_MV + 128000;
  float* Ppre  = ws + F_MV + 256000;
  // bf16 overlays (lifetimes disjoint — see layout comment)
  short* XtV    = (short*)(ws + F_J);
  short* XtI    = (short*)(ws + F_J + 3300000);
  short* WVb    = (short*)(ws + F_J + 6600000);
  short* WIb    = (short*)(ws + F_J + 8200000);
  short* NVb    = (short*)(ws + F_J + 6553600);
  short* Wob16  = (short*)(ws + F_J + 9830400);
  short* lanTb  = (short*)(ws + F_J + 10360000);
  short* Wtb    = (short*)(ws + F_D);
  short* tout16 = (short*)(ws + F_D + 1000000);
  short* ml2w16 = (short*)(ws + F_D + 1530000);

  float* out_vis  = (float*)d_out;
  float* out_lan  = out_vis + (size_t)B_*C_*HW;
  float* out_loss = out_lan + (size_t)B_*MT_*C_;

  float* Qf = QKVf;
  float* Kf = QKVf + (size_t)B_*HW*C_;
  float* Vf = QKVf + (size_t)2*B_*HW*C_;
  float* Qt = QKVt;
  float* Kt = QKVt + (size_t)B_*MT_*C_;
  float* Vt = QKVt + (size_t)2*B_*MT_*C_;

  // ---- geodesic 1 (vis ++ ir) ----
  k_pack_j1<<<dim3(32,7,B_),256,0,stream>>>(vis, ir, J);
  k_rowsq<<<B_*P1,64,0,stream>>>(J, sqb, P1);
  k_gram_dist<<<dim3(4,4,B_),256,0,stream>>>(J, sqb, Dm, P1);
  k_knn<P1><<<B_*P1,64,0,stream>>>(Dm, knn);
  k_fwx<P1,1024,10,4,0,100,100,100><<<B_,1024,0,stream>>>(Dm, knn, Mv, hs, hist);
  for (int it = 0; it < 2; it++){
    k_med_hist<<<256,256,0,stream>>>(Mv, B_*HW*HW, hs, hist);
    k_med_select<<<1,64,0,stream>>>(hs, hist, B_*HW*HW/2);
  }
  k_mgap<<<B_,256,0,stream>>>(Mv, W1, b1, sc, hs, alpha, bet);

  // ---- projections (bf16 MFMA paths) ----
  k_castw<<<(3*C_*C_/4+255)/256,256,0,stream>>>(vis_w, ir_w, WVb, WIb);
  k_cast<<<(C_*C_/4+255)/256,256,0,stream>>>(vout_w, Wob16, C_*C_);
  k_cast2<<<((4*C_*C_)/4+255)/256,256,0,stream>>>(t_w, ml_w, Wtb,
                                                  Wtb + (size_t)3*C_*C_,
                                                  3*C_*C_, C_*C_);
  k_xt2<<<dim3(32,4,B_),256,0,stream>>>(vis, ir, alpha, bet, XtV, XtI, feat);
  k_lanT<<<dim3(32,B_),256,0,stream>>>(lan, lanTb);
  k_convqkv_mfma<<<dim3(8,3,B_),256,0,stream>>>(XtV, XtI, WVb, WIb,
                                                vis_g, vis_be, ir_g, ir_be,
                                                alpha, bet, QKVf);
  k_textproj_mfma<<<dim3(8,12,4),256,0,stream>>>(lanTb, Wtb, t_b, QKVt, lanML);
  // Wtb dead now; cast late-GEMM weights into upper Dm region (audited free).
  k_cast2<<<((2*C_*C_)/4+255)/256,256,0,stream>>>(tout_w, ml2_w, tout16, ml2w16,
                                                  C_*C_, C_*C_);

  // ---- geodesic 2 (feat ++ lan) ----
  k_pack_j2<<<(B_*P2*C_+255)/256,256,0,stream>>>(feat, lan, J);
  k_rowsq<<<B_*P2,64,0,stream>>>(J, sqb, P2);
  k_gram_dist<<<dim3(2,2,B_),256,0,stream>>>(J, sqb, Dm, P2);
  k_knn<P2><<<B_*P2,64,0,stream>>>(Dm, knn);
  k_fwx<P2,960,4,4,100,0,MT_,100><<<B_,960,0,stream>>>(Dm, knn, Mt, hs+2, hist);
  for (int it = 0; it < 2; it++){
    k_med_hist<<<256,256,0,stream>>>(Mt, B_*MT_*HW, hs+2, hist);
    k_med_select<<<1,64,0,stream>>>(hs+2, hist, B_*MT_*HW/2);
  }
  k_mfixppre<<<(B_*MT_*HW+255)/256,256,0,stream>>>(Mt, hs+2, W2, b2, sc, Mfix, Ppre);
  k_sm20<<<(B_*HW+7)/8,256,0,stream>>>(Ppre, Pi2t);
  k_smT<<<B_*MT_,128,0,stream>>>(Ppre, Pt2i);

  // ---- manifold-learned matrices ----
  k_mlearn2<<<dim3(4,B_),256,0,stream>>>(Pi2t, Pt2i, lanML, ml_b, feat, MlT2I, T2b);
  k_tokproj_mfma<<<dim3(8,12),256,0,stream>>>(T2b, ml2w16, ml2_b, Mi2tL);

  // ---- attention scores (+ fused loss partials) ----
  k_w4ml<<<dim3(4,B_),256,0,stream>>>(W4, MlT2I, W4Ml);
  k_abt2<<<dim3(2,2,B_),256,0,stream>>>(Qt, Kf, MlT2I, S1, S2, MT_, HW);
  k_abt<<<dim3(2,2,B_),256,0,stream>>>(W4Ml, Kf, S3n, MT_, HW);
  k_abt2<<<dim3(7,1,B_),256,0,stream>>>(Qf, Kt, Mi2tL, S4a, S4b, HW, MT_);
  k_abt<<<dim3(2,1,B_),256,0,stream>>>(Mi2tL, Kt, S5, MT_, MT_);
  k_attA<<<B_*MT_,128,0,stream>>>(S1, S2, S3n, sc, Mfix, Av, pa);
  k_attB<<<B_*HW/8,256,0,stream>>>(S4a, S4b, S5, W5, sc, Mfix, Bv, pb);

  // ---- outputs ----
  k_nl<<<dim3(4,B_),256,0,stream>>>(Av, Pt2i, Vf, sc, NL);
  k_nv<<<dim3(4,B_),256,0,stream>>>(Bv, Pi2t, Vt, sc, NVb);
  k_tokproj_mfma<<<dim3(8,12),256,0,stream>>>(NL, tout16, tout_b, out_lan);
  k_convout_mfma<<<dim3(8,B_),256,0,stream>>>(NVb, Wob16, vout_b, out_vis);

  // ---- loss ----
  k_loss_final<<<1,256,0,stream>>>(pa, pb, out_loss);
}

// Round 20
// 2598.054 us; speedup vs baseline: 1.0556x; 1.0199x over previous
//
#include <hip/hip_runtime.h>
#include <hip/hip_bf16.h>
#include <math.h>

#define B_   64
#define C_   1024
#define HW   100
#define MT_  20
#define P1   200
#define P2   120
#define BIGF 1.0e6f
#define EPSF 1e-8f
#define SQC  32.0f

// ---------------- workspace layout (float offsets) ----------------
static constexpr size_t F_J    = 0;
static constexpr size_t N_J    = (size_t)B_*P1*C_;
static constexpr size_t F_D    = F_J + N_J;
static constexpr size_t N_D    = (size_t)B_*P1*P1;
static constexpr size_t F_SQ   = F_D + N_D;
static constexpr size_t N_SQ   = (size_t)B_*P1;
static constexpr size_t F_KNN  = F_SQ + N_SQ;
static constexpr size_t N_KNN  = (size_t)B_*P1*8;
static constexpr size_t F_MV   = F_KNN + N_KNN;
static constexpr size_t N_MV   = (size_t)B_*HW*HW;
static constexpr size_t F_MT   = F_MV + N_MV;
static constexpr size_t N_SM   = (size_t)B_*MT_*HW;
static constexpr size_t F_MFIX = F_MT + N_SM;
static constexpr size_t F_QKVF = F_MFIX + N_SM;
static constexpr size_t N_QKVF = (size_t)3*B_*HW*C_;
static constexpr size_t F_QKVT = F_QKVF + N_QKVF;
static constexpr size_t N_QKVT = (size_t)3*B_*MT_*C_;
static constexpr size_t F_FEAT = F_QKVT + N_QKVT;
static constexpr size_t N_FEAT = (size_t)B_*HW*C_;
static constexpr size_t N_SMC  = (size_t)B_*MT_*C_;
static constexpr size_t F_LANML= F_FEAT + N_FEAT;
static constexpr size_t F_T2   = F_LANML + N_SMC;
static constexpr size_t F_MI2TL= F_T2 + N_SMC;
static constexpr size_t F_S1   = F_MI2TL + N_SMC;
static constexpr size_t F_S2   = F_S1 + N_SM;
static constexpr size_t F_S4A  = F_S2 + N_SM;
static constexpr size_t F_S4B  = F_S4A + N_SM;
static constexpr size_t F_S5   = F_S4B + N_SM;
static constexpr size_t F_AV   = F_S5 + (size_t)B_*MT_*MT_;
static constexpr size_t F_BV   = F_AV + N_SM;
static constexpr size_t F_NL   = F_BV + N_SM;
static constexpr size_t F_AL   = F_NL + N_SMC;
static constexpr size_t F_BE   = F_AL + 64;
static constexpr size_t F_HS   = F_BE + 64;
static constexpr size_t F_HIST = F_HS + 8;
static constexpr size_t F_PA   = F_HIST + 1032;
static constexpr size_t F_PB   = F_PA + 6400;
// overlays: MlT2I = F_J ; S3 = F_D [..640,000)
//           Pi2t = F_MV ; Pt2i = F_MV+128000 ; Ppre = F_MV+256000
// bf16 overlays (audited disjoint lifetimes):
//   XtV=F_J ; XtI=+3,300,000 ; WVb=+6,600,000 ; WIb=+8,200,000
//   NVb=+6,553,600 ; Wob16=+9,830,400 ; lanTb=+10,360,000
//   Wtb=F_D ; tout16=F_D+1,000,000 ; ml2w16=F_D+1,530,000 (S3<=640,000 fl)

typedef __attribute__((ext_vector_type(8))) short bfrag;
typedef __attribute__((ext_vector_type(4))) short bhalf;
typedef __attribute__((ext_vector_type(4))) float f32x4;
#define MFMA_B16(a,b,c) __builtin_amdgcn_mfma_f32_16x16x32_bf16(a,b,c,0,0,0)

__device__ inline short f2bf(float x){
  __hip_bfloat16 h = __float2bfloat16(x);
  return *reinterpret_cast<short*>(&h);
}

// ---------------- kernels ----------------

__global__ __launch_bounds__(256) void k_pack_j1(const float* __restrict__ vis,
    const float* __restrict__ ir, float* __restrict__ J){
  __shared__ float tile[32][33];
  int c0 = blockIdx.x*32, p0 = blockIdx.y*32, b = blockIdx.z;
  int j = threadIdx.x & 31, i0 = threadIdx.x >> 5;
  for (int i = i0; i < 32; i += 8){
    int p = p0 + j;
    float v = 0.f;
    if (p < P1) v = (p < HW) ? vis[((size_t)b*C_ + c0+i)*HW + p]
                             : ir [((size_t)b*C_ + c0+i)*HW + (p-HW)];
    tile[i][j] = v;
  }
  __syncthreads();
  for (int i = i0; i < 32; i += 8){
    int p = p0 + i;
    if (p < P1) J[((size_t)b*P1 + p)*C_ + c0 + j] = tile[j][i];
  }
}

__global__ void k_pack_j2(const float* __restrict__ feat, const float* __restrict__ lan,
                          float* __restrict__ J){
  int idx = blockIdx.x*256 + threadIdx.x;
  if (idx >= B_*P2*C_) return;
  int c = idx & (C_-1);
  int p = (idx >> 10) % P2;
  int b = idx / (C_*P2);
  float v;
  if (p < HW) v = feat[((size_t)b*HW + p)*C_ + c];
  else        v = lan [((size_t)b*C_ + c)*MT_ + (p-HW)];
  J[idx] = v;
}

__global__ void k_rowsq(const float* __restrict__ J, float* __restrict__ sq, int P){
  int row = blockIdx.x;
  const float* r = J + (size_t)row*C_;
  float s = 0.f;
  for (int c = threadIdx.x; c < C_; c += 64){ float v = r[c]; s += v*v; }
  for (int o = 32; o > 0; o >>= 1) s += __shfl_down(s, o);
  if (threadIdx.x == 0) sq[row] = s;
}

// 64x64 tile, 4x4 acc, TRANSPOSED LDS [kk][row] (pad 68 => 16B-aligned b128
// reads; conflict-free read path). Same per-element kk order => bit-identical.
__global__ __launch_bounds__(256) void k_gram_dist(const float* __restrict__ J,
    const float* __restrict__ sq, float* __restrict__ D, int P){
  __shared__ __align__(16) float Xi[32][68];
  __shared__ __align__(16) float Xj[32][68];
  int b = blockIdx.z;
  int r0 = blockIdx.x*64, s0 = blockIdx.y*64;
  int tx = threadIdx.x & 15, ty = threadIdx.x >> 4;
  const float* Jb = J + (size_t)b*P*C_;
  float acc[4][4];
  #pragma unroll
  for (int u = 0; u < 4; u++)
    #pragma unroll
    for (int v = 0; v < 4; v++) acc[u][v] = 0.f;
  for (int c0 = 0; c0 < C_; c0 += 32){
    for (int e = threadIdx.x; e < 2048; e += 256){
      int rr = e >> 5, cc = e & 31;
      Xi[cc][rr] = (r0+rr < P) ? Jb[(size_t)(r0+rr)*C_ + c0+cc] : 0.f;
      Xj[cc][rr] = (s0+rr < P) ? Jb[(size_t)(s0+rr)*C_ + c0+cc] : 0.f;
    }
    __syncthreads();
    for (int kk = 0; kk < 32; kk++){
      float4 xr4 = *(const float4*)&Xi[kk][ty*4];
      float4 xs4 = *(const float4*)&Xj[kk][tx*4];
      float xr[4] = {xr4.x, xr4.y, xr4.z, xr4.w};
      float xs[4] = {xs4.x, xs4.y, xs4.z, xs4.w};
      #pragma unroll
      for (int u = 0; u < 4; u++)
        #pragma unroll
        for (int v = 0; v < 4; v++) acc[u][v] += xr[u]*xs[v];
    }
    __syncthreads();
  }
  #pragma unroll
  for (int u = 0; u < 4; u++){
    #pragma unroll
    for (int v = 0; v < 4; v++){
      int r = r0 + ty*4 + u, s = s0 + tx*4 + v;
      if (r < P && s < P){
        float d2 = sq[b*P+r] + sq[b*P+s] - 2.f*acc[u][v];
        D[((size_t)b*P + r)*P + s] = sqrtf(fmaxf(d2, 0.f));
      }
    }
  }
}

template<int P>
__global__ void k_knn(const float* __restrict__ D, int* __restrict__ knn){
  constexpr int NS = (P + 63)/64;
  int row = blockIdx.x;
  int i = row % P;
  const float* Dr = D + (size_t)row*P;
  float v[NS];
  #pragma unroll
  for (int t = 0; t < NS; t++){
    int j = threadIdx.x + t*64;
    float d = (j < P) ? Dr[j] : 4.0e6f;
    if (j == i) d += BIGF;
    v[t] = d;
  }
  for (int k = 0; k < 8; k++){
    float bv = 3.4e38f; int bj = 1 << 30;
    #pragma unroll
    for (int t = 0; t < NS; t++){
      int j = threadIdx.x + t*64;
      if (v[t] < bv){ bv = v[t]; bj = j; }
    }
    for (int o = 32; o > 0; o >>= 1){
      float ov = __shfl_xor(bv, o);
      int   oj = __shfl_xor(bj, o);
      if (ov < bv || (ov == bv && oj < bj)){ bv = ov; bj = oj; }
    }
    if (threadIdx.x == 0) knn[(size_t)row*8 + k] = bj;
    if ((bj & 63) == (int)threadIdx.x){
      #pragma unroll
      for (int t = 0; t < NS; t++) if (t == (bj >> 6)) v[t] = 3.9e38f;
    }
  }
}

// Fused buildw + register-FW + minmax(window) -> normalized output.
template<int P, int NT, int RP, int CP, int R0, int C0, int RR, int CC>
__global__ __launch_bounds__(1024) void k_fwx(const float* __restrict__ D,
    const int* __restrict__ knn, float* __restrict__ outM){
  constexpr int PR = P/RP;
  constexpr int PC = P/CP;
  constexpr int NTH = PR*PC;
  __shared__ float rowk[P], colk[P];
  __shared__ int kl[P*8];
  __shared__ float rmn[1024], rmx[1024];
  int b = blockIdx.x;
  const float* Db = D + (size_t)b*P*P;
  const int* kb = knn + (size_t)b*P*8;
  int tid = threadIdx.x;
  bool act = tid < NTH;
  int pi = tid / PC, pj = tid - pi*PC;
  int i0 = pi*RP, j0 = pj*CP;
  for (int e = tid; e < P*8; e += NT) kl[e] = kb[e];
  __syncthreads();
  float w[RP][CP];
  if (act){
    #pragma unroll
    for (int r = 0; r < RP; r++){
      float4 v = *(const float4*)(Db + (size_t)(i0+r)*P + j0);
      w[r][0]=v.x; w[r][1]=v.y; w[r][2]=v.z; w[r][3]=v.w;
      int i = i0 + r;
      #pragma unroll
      for (int c = 0; c < CP; c++){
        int j = j0 + c;
        if (i == j) w[r][c] = 0.f;
        else {
          const int* ki = &kl[i*8];
          const int* kj = &kl[j*8];
          bool e = false;
          #pragma unroll
          for (int k = 0; k < 8; k++) e = e || (ki[k] == j) || (kj[k] == i);
          if (!e) w[r][c] = BIGF;
        }
      }
    }
  }
  __syncthreads();
  for (int k = 0; k < P; k++){
    if (act){
      #pragma unroll
      for (int r = 0; r < RP; r++){
        if (i0 + r == k)
          *(float4*)(rowk + j0) = make_float4(w[r][0],w[r][1],w[r][2],w[r][3]);
      }
      #pragma unroll
      for (int c = 0; c < CP; c++){
        if (j0 + c == k){
          #pragma unroll
          for (int r = 0; r < RP; r++) colk[i0+r] = w[r][c];
        }
      }
    }
    __syncthreads();
    if (act){
      float4 rk4 = *(const float4*)(rowk + j0);
      float rk[4] = {rk4.x, rk4.y, rk4.z, rk4.w};
      float ck[RP];
      #pragma unroll
      for (int r = 0; r < RP; r++) ck[r] = colk[i0+r];
      #pragma unroll
      for (int r = 0; r < RP; r++)
        #pragma unroll
        for (int c = 0; c < CP; c++)
          w[r][c] = fminf(w[r][c], ck[r] + rk[c]);
    }
    __syncthreads();
  }
  float mn = 3.4e38f, mx = -3.4e38f;
  if (act){
    #pragma unroll
    for (int r = 0; r < RP; r++){
      int i = i0 + r;
      if (i >= R0 && i < R0+RR){
        #pragma unroll
        for (int c = 0; c < CP; c++){
          int j = j0 + c;
          if (j >= C0 && j < C0+CC){
            mn = fminf(mn, w[r][c]); mx = fmaxf(mx, w[r][c]);
          }
        }
      }
    }
  }
  rmn[tid] = mn; rmx[tid] = mx;
  __syncthreads();
  for (int o = 512; o > 0; o >>= 1){
    if (tid < o && tid + o < NT){
      rmn[tid] = fminf(rmn[tid], rmn[tid+o]);
      rmx[tid] = fmaxf(rmx[tid], rmx[tid+o]);
    }
    __syncthreads();
  }
  mn = rmn[0]; mx = rmx[0];
  float inv = 1.f/(mx - mn + EPSF);
  if (act){
    #pragma unroll
    for (int r = 0; r < RP; r++){
      int i = i0 + r;
      if (i >= R0 && i < R0+RR){
        #pragma unroll
        for (int c = 0; c < CP; c++){
          int j = j0 + c;
          if (j >= C0 && j < C0+CC)
            outM[((size_t)b*RR + (i-R0))*CC + (j-C0)] = (w[r][c] - mn)*inv;
        }
      }
    }
  }
}

__global__ void k_med_init(float* hs){ if (threadIdx.x == 0){ hs[0] = 0.f; hs[1] = 1.0f; } }

__global__ __launch_bounds__(256) void k_med_hist(const float* __restrict__ x, int N,
                           const float* __restrict__ hs, unsigned* __restrict__ hist){
  __shared__ unsigned lh[1025];
  for (int i = threadIdx.x; i < 1025; i += 256) lh[i] = 0u;
  __syncthreads();
  float lo = hs[0], hi = hs[1];
  float scale = 1024.f/(hi - lo);
  unsigned below = 0;
  int idx = blockIdx.x*256 + threadIdx.x;
  int stride = gridDim.x*256;
  for (int i = idx; i < N; i += stride){
    float v = x[i];
    if (v < lo) below++;
    else if (v < hi){
      int bn = (int)((v - lo)*scale);
      if (bn > 1023) bn = 1023;
      atomicAdd(&lh[bn], 1u);
    }
  }
  for (int o = 32; o > 0; o >>= 1) below += __shfl_down(below, o);
  if ((threadIdx.x & 63) == 0 && below) atomicAdd(&lh[1024], below);
  __syncthreads();
  for (int i = threadIdx.x; i < 1025; i += 256){
    unsigned v = lh[i];
    if (v) atomicAdd(&hist[i], v);
  }
}

__global__ void k_med_select(float* hs, const unsigned* __restrict__ hist, int k){
  if (threadIdx.x != 0) return;
  float lo = hs[0], hi = hs[1], w = (hi - lo)*(1.f/1024.f);
  unsigned cum = hist[1024];
  int bf = 1023;
  for (int bn = 0; bn < 1024; bn++){
    unsigned h = hist[bn];
    if (cum + h > (unsigned)k){ bf = bn; break; }
    cum += h;
  }
  hs[0] = lo + bf*w; hs[1] = lo + (bf+1)*w;
}

__global__ __launch_bounds__(256) void k_mgap(const float* __restrict__ Mv,
    const float* __restrict__ W1, const float* __restrict__ b1,
    const float* __restrict__ sc, const float* __restrict__ hs,
    float* __restrict__ alpha, float* __restrict__ bet){
  __shared__ float sr[256];
  int b = blockIdx.x;
  float lam1s = 1.f/(1.f + expf(-sc[0]));
  float sig = 0.5f*(hs[0] + hs[1]);
  float inv2s = 1.f/(2.f*sig*sig);
  const float* Mb = Mv + (size_t)b*HW*HW;
  float s = 0.f;
  for (int e = threadIdx.x; e < HW*HW; e += 256){
    float v = Mb[e];
    float f = expf(-v*v*inv2s);
    s += lam1s*f + (1.f - lam1s)*(W1[e]*f + b1[e]);
  }
  sr[threadIdx.x] = s; __syncthreads();
  for (int o = 128; o > 0; o >>= 1){
    if ((int)threadIdx.x < o) sr[threadIdx.x] += sr[threadIdx.x+o];
    __syncthreads();
  }
  if (threadIdx.x == 0){
    float mg = sr[0]*(1.f/(HW*HW));
    alpha[b] = 1.f/(1.f + expf(-(sc[8]*mg + sc[9])));
    bet[b]   = 1.f/(1.f + expf(-(sc[10]*mg + sc[11])));
  }
}

__global__ void k_castw(const float* __restrict__ a, const float* __restrict__ b,
                        short* __restrict__ oa, short* __restrict__ ob){
  int i = (blockIdx.x*256 + threadIdx.x)*4;
  if (i >= 3*C_*C_) return;
  float4 va = *(const float4*)(a + i);
  float4 vb = *(const float4*)(b + i);
  short ra[4] = { f2bf(va.x), f2bf(va.y), f2bf(va.z), f2bf(va.w) };
  short rb[4] = { f2bf(vb.x), f2bf(vb.y), f2bf(vb.z), f2bf(vb.w) };
  *(bhalf*)(oa + i) = *(bhalf*)ra;
  *(bhalf*)(ob + i) = *(bhalf*)rb;
}

__global__ void k_cast(const float* __restrict__ a, short* __restrict__ oa, int n){
  int i = (blockIdx.x*256 + threadIdx.x)*4;
  if (i >= n) return;
  float4 va = *(const float4*)(a + i);
  short ra[4] = { f2bf(va.x), f2bf(va.y), f2bf(va.z), f2bf(va.w) };
  *(bhalf*)(oa + i) = *(bhalf*)ra;
}

__global__ void k_cast2(const float* __restrict__ a, const float* __restrict__ b,
                        short* __restrict__ oa, short* __restrict__ ob,
                        int n1, int n2){
  int i = (blockIdx.x*256 + threadIdx.x)*4;
  if (i < n1){
    float4 va = *(const float4*)(a + i);
    short ra[4] = { f2bf(va.x), f2bf(va.y), f2bf(va.z), f2bf(va.w) };
    *(bhalf*)(oa + i) = *(bhalf*)ra;
  } else if (i < n1 + n2){
    int k = i - n1;
    float4 vb = *(const float4*)(b + k);
    short rb[4] = { f2bf(vb.x), f2bf(vb.y), f2bf(vb.z), f2bf(vb.w) };
    *(bhalf*)(ob + k) = *(bhalf*)rb;
  }
}

// fused transpose [b][c][t] -> [b][t][c] bf16 for vis & ir, + feat (f32) output
__global__ __launch_bounds__(256) void k_xt2(const float* __restrict__ V,
    const float* __restrict__ I, const float* __restrict__ alpha,
    const float* __restrict__ bet, short* __restrict__ XtV,
    short* __restrict__ XtI, float* __restrict__ feat){
  __shared__ float tv[32][33], ti[32][33];
  int c0 = blockIdx.x*32, t0 = blockIdx.y*32, b = blockIdx.z;
  int j = threadIdx.x & 31, i0 = threadIdx.x >> 5;
  for (int i = i0; i < 32; i += 8){
    int t = t0 + j;
    float a = 0.f, c = 0.f;
    if (t < HW){
      a = V[((size_t)b*C_ + c0+i)*HW + t];
      c = I[((size_t)b*C_ + c0+i)*HW + t];
    }
    tv[i][j] = a; ti[i][j] = c;
  }
  __syncthreads();
  float al = alpha[b], bt = bet[b];
  for (int i = i0; i < 32; i += 8){
    int t = t0 + i;
    if (t < HW){
      float fv = tv[j][i], fi = ti[j][i];
      size_t off = ((size_t)b*HW + t)*C_ + c0 + j;
      XtV[off] = f2bf(fv);
      XtI[off] = f2bf(fi);
      feat[off] = al*fv + bt*fi;
    }
  }
}

__global__ __launch_bounds__(256) void k_lanT(const float* __restrict__ lan,
                                              short* __restrict__ lanT){
  __shared__ float tile[32][21];
  int c0 = blockIdx.x*32, b = blockIdx.y;
  for (int e = threadIdx.x; e < 32*MT_; e += 256){
    int c = e / MT_, t = e - c*MT_;
    tile[c][t] = lan[((size_t)b*C_ + c0+c)*MT_ + t];
  }
  __syncthreads();
  for (int e = threadIdx.x; e < 32*MT_; e += 256){
    int t = e >> 5, c = e & 31;
    lanT[((size_t)(b*MT_ + t))*C_ + c0 + c] = f2bf(tile[c][t]);
  }
}

// Direct global->register MFMA conv1x1 + IN + ReLU + alpha/beta (FROZEN, 425us).
__global__ __launch_bounds__(256) void k_convqkv_mfma(
    const short* __restrict__ XtV, const short* __restrict__ XtI,
    const short* __restrict__ WV,  const short* __restrict__ WI,
    const float* __restrict__ vg, const float* __restrict__ vbe,
    const float* __restrict__ ig, const float* __restrict__ ibe,
    const float* __restrict__ alpha, const float* __restrict__ bet,
    float* __restrict__ out){
  int m0 = blockIdx.x*128;
  int wsel = blockIdx.y;
  int b = blockIdx.z;
  int tid = threadIdx.x;
  int lane = tid & 63, w = tid >> 6;
  int lg = lane >> 4, lr = lane & 15;
  f32x4 acc[7][2][2];
  #pragma unroll
  for (int tf = 0; tf < 7; tf++)
    #pragma unroll
    for (int mf = 0; mf < 2; mf++)
      #pragma unroll
      for (int md = 0; md < 2; md++)
        acc[tf][mf][md] = (f32x4){0.f,0.f,0.f,0.f};
  const short* xvp = XtV + (size_t)b*HW*C_ + (size_t)lr*C_ + lg*8;
  const short* xip = XtI + (size_t)b*HW*C_ + (size_t)lr*C_ + lg*8;
  const short* wvp = WV + (size_t)wsel*C_*C_ + (size_t)(m0 + w*32 + lr)*C_ + lg*8;
  const short* wip = WI + (size_t)wsel*C_*C_ + (size_t)(m0 + w*32 + lr)*C_ + lg*8;
  const bfrag zf = {0,0,0,0,0,0,0,0};
  for (int k0 = 0; k0 < C_; k0 += 32){
    bfrag bw0v = *(const bfrag*)(wvp + k0);
    bfrag bw1v = *(const bfrag*)(wvp + (size_t)16*C_ + k0);
    bfrag bw0i = *(const bfrag*)(wip + k0);
    bfrag bw1i = *(const bfrag*)(wip + (size_t)16*C_ + k0);
    #pragma unroll
    for (int tf = 0; tf < 7; tf++){
      bfrag axv = zf, axi = zf;
      if (tf*16 + lr < HW){
        axv = *(const bfrag*)(xvp + (size_t)tf*16*C_ + k0);
        axi = *(const bfrag*)(xip + (size_t)tf*16*C_ + k0);
      }
      acc[tf][0][0] = MFMA_B16(axv, bw0v, acc[tf][0][0]);
      acc[tf][1][0] = MFMA_B16(axv, bw1v, acc[tf][1][0]);
      acc[tf][0][1] = MFMA_B16(axi, bw0i, acc[tf][0][1]);
      acc[tf][1][1] = MFMA_B16(axi, bw1i, acc[tf][1][1]);
    }
  }
  float al = alpha[b], bt = bet[b];
  float* ob = out + ((size_t)(wsel*B_ + b))*HW*C_;
  #pragma unroll
  for (int mf = 0; mf < 2; mf++){
    int m = m0 + w*32 + mf*16 + lr;
    float s1v=0.f,s2v=0.f,s1i=0.f,s2i=0.f;
    #pragma unroll
    for (int tf = 0; tf < 7; tf++){
      #pragma unroll
      for (int r = 0; r < 4; r++){
        int t = tf*16 + lg*4 + r;
        if (t < HW){
          float yv = acc[tf][mf][0][r], yi = acc[tf][mf][1][r];
          s1v += yv; s2v += yv*yv; s1i += yi; s2i += yi*yi;
        }
      }
    }
    s1v += __shfl_xor(s1v,16); s1v += __shfl_xor(s1v,32);
    s2v += __shfl_xor(s2v,16); s2v += __shfl_xor(s2v,32);
    s1i += __shfl_xor(s1i,16); s1i += __shfl_xor(s1i,32);
    s2i += __shfl_xor(s2i,16); s2i += __shfl_xor(s2i,32);
    float muv = s1v*0.01f, varv = s2v*0.01f - muv*muv;
    float mui = s1i*0.01f, vari = s2i*0.01f - mui*mui;
    float scv = vg[wsel*C_+m]/sqrtf(varv+1e-5f);
    float shv = vbe[wsel*C_+m] - muv*scv;
    float sci = ig[wsel*C_+m]/sqrtf(vari+1e-5f);
    float shi = ibe[wsel*C_+m] - mui*sci;
    #pragma unroll
    for (int tf = 0; tf < 7; tf++){
      #pragma unroll
      for (int r = 0; r < 4; r++){
        int t = tf*16 + lg*4 + r;
        if (t < HW){
          float yv = fmaxf(acc[tf][mf][0][r]*scv + shv, 0.f);
          float yi = fmaxf(acc[tf][mf][1][r]*sci + shi, 0.f);
          ob[(size_t)t*C_ + m] = al*yv + bt*yi;
        }
      }
    }
  }
}

// S3[b][i][j] = sum_c MlT2I[b][i][c] * Kf[b][j][c]; on-the-fly bf16 cast.
__global__ __launch_bounds__(256) void k_s3_mfma(
    const float* __restrict__ Ml, const float* __restrict__ Kf,
    float* __restrict__ S3){
  int jt = blockIdx.x, b = blockIdx.y;
  int tid = threadIdx.x;
  int lane = tid & 63, w = tid >> 6;
  int lg = lane >> 4, lr = lane & 15;
  f32x4 acc[7];
  #pragma unroll
  for (int tf = 0; tf < 7; tf++) acc[tf] = (f32x4){0.f,0.f,0.f,0.f};
  const float* Ab = Ml + (size_t)b*HW*C_;
  const float* Bb = Kf + (size_t)b*HW*C_;
  const bfrag zf = {0,0,0,0,0,0,0,0};
  int j = jt*64 + w*16 + lr;
  for (int k0 = 0; k0 < C_; k0 += 32){
    int kc = k0 + lg*8;
    bfrag bw = zf;
    if (j < HW){
      float4 u = *(const float4*)(Bb + (size_t)j*C_ + kc);
      float4 v = *(const float4*)(Bb + (size_t)j*C_ + kc + 4);
      bw[0]=f2bf(u.x); bw[1]=f2bf(u.y); bw[2]=f2bf(u.z); bw[3]=f2bf(u.w);
      bw[4]=f2bf(v.x); bw[5]=f2bf(v.y); bw[6]=f2bf(v.z); bw[7]=f2bf(v.w);
    }
    #pragma unroll
    for (int tf = 0; tf < 7; tf++){
      bfrag fa = zf;
      int i = tf*16 + lr;
      if (i < HW){
        float4 u = *(const float4*)(Ab + (size_t)i*C_ + kc);
        float4 v = *(const float4*)(Ab + (size_t)i*C_ + kc + 4);
        fa[0]=f2bf(u.x); fa[1]=f2bf(u.y); fa[2]=f2bf(u.z); fa[3]=f2bf(u.w);
        fa[4]=f2bf(v.x); fa[5]=f2bf(v.y); fa[6]=f2bf(v.z); fa[7]=f2bf(v.w);
      }
      acc[tf] = MFMA_B16(fa, bw, acc[tf]);
    }
  }
  float* ob = S3 + (size_t)b*HW*HW;
  #pragma unroll
  for (int tf = 0; tf < 7; tf++){
    #pragma unroll
    for (int r = 0; r < 4; r++){
      int i = tf*16 + lg*4 + r;
      if (i < HW && j < HW) ob[(size_t)i*HW + j] = acc[tf][r];
    }
  }
}

// Packed-row GEMM: out[row][n] = sum_c X[row][c]*W16[n][c] + bias[n], 1280 rows.
__global__ __launch_bounds__(256) void k_tokproj_mfma(
    const float* __restrict__ X, const short* __restrict__ W16,
    const float* __restrict__ bias, float* __restrict__ out){
  constexpr int NROW = B_*MT_;
  int n0 = blockIdx.x*128;
  int t0 = blockIdx.y*112;
  int tid = threadIdx.x;
  int lane = tid & 63, w = tid >> 6;
  int lg = lane >> 4, lr = lane & 15;
  f32x4 acc[7][2];
  #pragma unroll
  for (int tf = 0; tf < 7; tf++)
    #pragma unroll
    for (int mf = 0; mf < 2; mf++)
      acc[tf][mf] = (f32x4){0.f,0.f,0.f,0.f};
  const short* wp = W16 + (size_t)(n0 + w*32 + lr)*C_ + lg*8;
  const bfrag zf = {0,0,0,0,0,0,0,0};
  for (int k0 = 0; k0 < C_; k0 += 32){
    bfrag bw0 = *(const bfrag*)(wp + k0);
    bfrag bw1 = *(const bfrag*)(wp + (size_t)16*C_ + k0);
    #pragma unroll
    for (int tf = 0; tf < 7; tf++){
      bfrag ax = zf;
      int row = t0 + tf*16 + lr;
      if (row < NROW){
        const float* ap = X + (size_t)row*C_ + k0 + lg*8;
        float4 u = *(const float4*)ap;
        float4 v = *(const float4*)(ap + 4);
        ax[0]=f2bf(u.x); ax[1]=f2bf(u.y); ax[2]=f2bf(u.z); ax[3]=f2bf(u.w);
        ax[4]=f2bf(v.x); ax[5]=f2bf(v.y); ax[6]=f2bf(v.z); ax[7]=f2bf(v.w);
      }
      acc[tf][0] = MFMA_B16(ax, bw0, acc[tf][0]);
      acc[tf][1] = MFMA_B16(ax, bw1, acc[tf][1]);
    }
  }
  #pragma unroll
  for (int mf = 0; mf < 2; mf++){
    int n = n0 + w*32 + mf*16 + lr;
    float bv = bias[n];
    #pragma unroll
    for (int tf = 0; tf < 7; tf++){
      #pragma unroll
      for (int r = 0; r < 4; r++){
        int row = t0 + tf*16 + lg*4 + r;
        if (row < NROW) out[(size_t)row*C_ + n] = acc[tf][mf][r] + bv;
      }
    }
  }
}

#define TPAD 36
__global__ __launch_bounds__(256) void k_convout_mfma(
    const short* __restrict__ NVb, const short* __restrict__ Wb,
    const float* __restrict__ bias, float* __restrict__ out){
  __shared__ short xs[112*TPAD];
  __shared__ short wsm[128*TPAD];
  int n0 = blockIdx.x*128, b = blockIdx.y;
  int tid = threadIdx.x;
  int lane = tid & 63, w = tid >> 6;
  int lg = lane >> 4, lr = lane & 15;
  for (int e = tid; e < 12*TPAD; e += 256) xs[100*TPAD + e] = 0;
  f32x4 acc[7][2];
  #pragma unroll
  for (int tf = 0; tf < 7; tf++)
    #pragma unroll
    for (int nf = 0; nf < 2; nf++)
      acc[tf][nf] = (f32x4){0.f,0.f,0.f,0.f};
  const short* xg = NVb + (size_t)b*HW*C_;
  const short* wg = Wb + (size_t)n0*C_;
  int rr0 = tid >> 3, kk = (tid & 7)*4;
  for (int k0 = 0; k0 < C_; k0 += 32){
    __syncthreads();
    for (int rr = rr0; rr < HW; rr += 32)
      *(uint2*)&xs[rr*TPAD + kk] = *(const uint2*)(xg + (size_t)rr*C_ + k0 + kk);
    for (int rr = rr0; rr < 128; rr += 32)
      *(uint2*)&wsm[rr*TPAD + kk] = *(const uint2*)(wg + (size_t)rr*C_ + k0 + kk);
    __syncthreads();
    const short* pw0 = &wsm[(w*32 + lr)*TPAD + lg*4];
    const short* pw1 = &wsm[(w*32 + 16 + lr)*TPAD + lg*4];
    bhalf l0, h0;
    l0 = *(const bhalf*)pw0; h0 = *(const bhalf*)(pw0 + 16);
    bfrag aw0 = {l0[0],l0[1],l0[2],l0[3],h0[0],h0[1],h0[2],h0[3]};
    l0 = *(const bhalf*)pw1; h0 = *(const bhalf*)(pw1 + 16);
    bfrag aw1 = {l0[0],l0[1],l0[2],l0[3],h0[0],h0[1],h0[2],h0[3]};
    #pragma unroll
    for (int tf = 0; tf < 7; tf++){
      const short* pb = &xs[(tf*16 + lr)*TPAD + lg*4];
      bhalf bl_ = *(const bhalf*)pb, bh_ = *(const bhalf*)(pb + 16);
      bfrag bx = {bl_[0],bl_[1],bl_[2],bl_[3],bh_[0],bh_[1],bh_[2],bh_[3]};
      acc[tf][0] = MFMA_B16(aw0, bx, acc[tf][0]);
      acc[tf][1] = MFMA_B16(aw1, bx, acc[tf][1]);
    }
  }
  float* ob = out + (size_t)b*C_*HW;
  #pragma unroll
  for (int nf = 0; nf < 2; nf++){
    #pragma unroll
    for (int r = 0; r < 4; r++){
      int n = n0 + w*32 + nf*16 + lg*4 + r;
      float bv = bias[n];
      #pragma unroll
      for (int tf = 0; tf < 7; tf++){
        int t = tf*16 + lr;
        if (t < HW) ob[(size_t)n*HW + t] = acc[tf][nf][r] + bv;
      }
    }
  }
}

__global__ __launch_bounds__(256) void k_textproj_mfma(
    const short* __restrict__ lanT, const short* __restrict__ Wt,
    const float* __restrict__ tb, float* __restrict__ QKVt, float* __restrict__ lanML){
  constexpr int NROW = B_*MT_;
  __shared__ short xs[112*TPAD];
  __shared__ short wsm[128*TPAD];
  int m0 = blockIdx.x*128;
  int t0 = blockIdx.y*112;
  int wsel = blockIdx.z;
  int tid = threadIdx.x;
  int lane = tid & 63, w = tid >> 6;
  int lg = lane >> 4, lr = lane & 15;
  f32x4 acc[7][2];
  #pragma unroll
  for (int tf = 0; tf < 7; tf++)
    #pragma unroll
    for (int mf = 0; mf < 2; mf++)
      acc[tf][mf] = (f32x4){0.f,0.f,0.f,0.f};
  const short* wg = Wt + (size_t)wsel*C_*C_ + (size_t)m0*C_;
  int rr0 = tid >> 3, kk = (tid & 7)*4;
  for (int k0 = 0; k0 < C_; k0 += 32){
    __syncthreads();
    for (int rr = rr0; rr < 112; rr += 32){
      int row = t0 + rr;
      uint2 v = make_uint2(0u, 0u);
      if (row < NROW) v = *(const uint2*)(lanT + (size_t)row*C_ + k0 + kk);
      *(uint2*)&xs[rr*TPAD + kk] = v;
    }
    for (int rr = rr0; rr < 128; rr += 32)
      *(uint2*)&wsm[rr*TPAD + kk] = *(const uint2*)(wg + (size_t)rr*C_ + k0 + kk);
    __syncthreads();
    const short* pw0 = &wsm[(w*32 + lr)*TPAD + lg*4];
    const short* pw1 = &wsm[(w*32 + 16 + lr)*TPAD + lg*4];
    bhalf l0, h0;
    l0 = *(const bhalf*)pw0; h0 = *(const bhalf*)(pw0 + 16);
    bfrag bw0 = {l0[0],l0[1],l0[2],l0[3],h0[0],h0[1],h0[2],h0[3]};
    l0 = *(const bhalf*)pw1; h0 = *(const bhalf*)(pw1 + 16);
    bfrag bw1 = {l0[0],l0[1],l0[2],l0[3],h0[0],h0[1],h0[2],h0[3]};
    #pragma unroll
    for (int tf = 0; tf < 7; tf++){
      const short* pa = &xs[(tf*16 + lr)*TPAD + lg*4];
      bhalf al_ = *(const bhalf*)pa, ah_ = *(const bhalf*)(pa + 16);
      bfrag ax = {al_[0],al_[1],al_[2],al_[3],ah_[0],ah_[1],ah_[2],ah_[3]};
      acc[tf][0] = MFMA_B16(ax, bw0, acc[tf][0]);
      acc[tf][1] = MFMA_B16(ax, bw1, acc[tf][1]);
    }
  }
  bool isml = (wsel == 3);
  #pragma unroll
  for (int mf = 0; mf < 2; mf++){
    int m = m0 + w*32 + mf*16 + lr;
    float bv = isml ? 0.f : tb[wsel*C_ + m];
    #pragma unroll
    for (int tf = 0; tf < 7; tf++){
      #pragma unroll
      for (int r = 0; r < 4; r++){
        int row = t0 + tf*16 + lg*4 + r;
        if (row < NROW){
          float v = acc[tf][mf][r] + bv;
          if (!isml) v = fmaxf(v, 0.f);
          if (isml) lanML[(size_t)row*C_ + m] = v;
          else      QKVt[((size_t)wsel*NROW + row)*C_ + m] = v;
        }
      }
    }
  }
}

__global__ void k_mfixppre(const float* __restrict__ Mt, const float* __restrict__ hs2,
                           const float* __restrict__ W2, const float* __restrict__ b2,
                           const float* __restrict__ sc,
                           float* __restrict__ Mfix, float* __restrict__ Ppre){
  int idx = blockIdx.x*256 + threadIdx.x;
  if (idx >= B_*MT_*HW) return;
  int i = idx % HW;
  int j = (idx/HW) % MT_;
  int b = idx/(MT_*HW);
  float sig = 0.5f*(hs2[0] + hs2[1]);
  float v = Mt[idx];
  float f = expf(-v*v/(2.f*sig*sig));
  Mfix[idx] = f;
  float lam2s = 1.f/(1.f + expf(-sc[1]));
  Ppre[((size_t)b*HW + i)*MT_ + j] = lam2s*f + (1.f - lam2s)*(W2[i*MT_ + j]*f + b2[i*MT_ + j]);
}

__global__ __launch_bounds__(256) void k_sm20(const float* __restrict__ Ppre, float* __restrict__ Pi2t){
  int row = blockIdx.x*8 + (threadIdx.x >> 5);
  int lane = threadIdx.x & 31;
  if (row >= B_*HW) return;
  float v = (lane < MT_) ? Ppre[(size_t)row*MT_ + lane]*(1.f/SQC) : -3.4e38f;
  float m = v;
  for (int o = 16; o > 0; o >>= 1) m = fmaxf(m, __shfl_xor(m, o, 32));
  float e = (lane < MT_) ? expf(v - m) : 0.f;
  float s = e;
  for (int o = 16; o > 0; o >>= 1) s += __shfl_xor(s, o, 32);
  if (lane < MT_) Pi2t[(size_t)row*MT_ + lane] = e/s;
}

__global__ __launch_bounds__(128) void k_smT(const float* __restrict__ Ppre, float* __restrict__ Pt2i){
  __shared__ float sm[128], ss[128];
  int bj = blockIdx.x; int b = bj/MT_, j = bj % MT_;
  int i = threadIdx.x;
  float v = (i < HW) ? Ppre[((size_t)b*HW + i)*MT_ + j]*(1.f/SQC) : -3.4e38f;
  sm[i] = v; __syncthreads();
  for (int o = 64; o > 0; o >>= 1){
    if (i < o) sm[i] = fmaxf(sm[i], sm[i+o]);
    __syncthreads();
  }
  float m = sm[0];
  float e = (i < HW) ? expf(v - m) : 0.f;
  ss[i] = e; __syncthreads();
  for (int o = 64; o > 0; o >>= 1){
    if (i < o) ss[i] += ss[i+o];
    __syncthreads();
  }
  if (i < HW) Pt2i[((size_t)b*MT_ + j)*HW + i] = e/ss[0];
}

__global__ __launch_bounds__(256) void k_mlearn_t2i(const float* __restrict__ Pi2t,
    const float* __restrict__ lanML, const float* __restrict__ mlb, float* __restrict__ out){
  __shared__ float sP[HW][MT_];
  int b = blockIdx.y; int m = blockIdx.x*256 + threadIdx.x;
  for (int e = threadIdx.x; e < HW*MT_; e += 256) sP[e/MT_][e%MT_] = Pi2t[(size_t)b*HW*MT_ + e];
  __syncthreads();
  float vL[MT_];
  #pragma unroll
  for (int j = 0; j < MT_; j++) vL[j] = lanML[((size_t)b*MT_ + j)*C_ + m];
  float bb = mlb[m];
  for (int i = 0; i < HW; i++){
    float a = bb;
    #pragma unroll
    for (int j = 0; j < MT_; j++) a += sP[i][j]*vL[j];
    out[((size_t)b*HW + i)*C_ + m] = a;
  }
}

__global__ __launch_bounds__(256) void k_t2(const float* __restrict__ Pt2i,
    const float* __restrict__ feat, float* __restrict__ T2o){
  __shared__ float sP[MT_][HW];
  int b = blockIdx.y; int m = blockIdx.x*256 + threadIdx.x;
  for (int e = threadIdx.x; e < MT_*HW; e += 256) sP[e/HW][e%HW] = Pt2i[(size_t)b*MT_*HW + e];
  __syncthreads();
  float acc[MT_];
  #pragma unroll
  for (int j = 0; j < MT_; j++) acc[j] = 0.f;
  for (int i = 0; i < HW; i++){
    float f = feat[((size_t)b*HW + i)*C_ + m];
    #pragma unroll
    for (int j = 0; j < MT_; j++) acc[j] += sP[j][i]*f;
  }
  #pragma unroll
  for (int j = 0; j < MT_; j++) T2o[((size_t)b*MT_ + j)*C_ + m] = acc[j];
}

__global__ __launch_bounds__(256) void k_abt(const float* __restrict__ X,
    const float* __restrict__ Y, float* __restrict__ out, int I, int Jd){
  __shared__ float Xs[16][33], Ys[64][33];
  int i0 = blockIdx.x*16, j0 = blockIdx.y*64, b = blockIdx.z;
  int jl = threadIdx.x & 63, ig = threadIdx.x >> 6;
  float acc[4] = {0.f,0.f,0.f,0.f};
  const float* Xb = X + (size_t)b*I*C_;
  const float* Yb = Y + (size_t)b*Jd*C_;
  for (int c0 = 0; c0 < C_; c0 += 32){
    for (int e = threadIdx.x; e < 512; e += 256){
      int r = e >> 5, cc = e & 31;
      Xs[r][cc] = (i0+r < I) ? Xb[(size_t)(i0+r)*C_ + c0+cc] : 0.f;
    }
    for (int e = threadIdx.x; e < 2048; e += 256){
      int r = e >> 5, cc = e & 31;
      Ys[r][cc] = (j0+r < Jd) ? Yb[(size_t)(j0+r)*C_ + c0+cc] : 0.f;
    }
    __syncthreads();
    for (int kk = 0; kk < 32; kk++){
      float y = Ys[jl][kk];
      #pragma unroll
      for (int k = 0; k < 4; k++) acc[k] += Xs[ig*4+k][kk]*y;
    }
    __syncthreads();
  }
  #pragma unroll
  for (int k = 0; k < 4; k++){
    int i = i0 + ig*4 + k, j = j0 + jl;
    if (i < I && j < Jd) out[((size_t)b*I + i)*Jd + j] = acc[k];
  }
}

__global__ __launch_bounds__(256) void k_abt2(const float* __restrict__ X,
    const float* __restrict__ Y1, const float* __restrict__ Y2,
    float* __restrict__ out1, float* __restrict__ out2, int I, int Jd){
  __shared__ float Xs[16][33], Y1s[64][33], Y2s[64][33];
  int i0 = blockIdx.x*16, j0 = blockIdx.y*64, b = blockIdx.z;
  int jl = threadIdx.x & 63, ig = threadIdx.x >> 6;
  float acc1[4] = {0.f,0.f,0.f,0.f};
  float acc2[4] = {0.f,0.f,0.f,0.f};
  const float* Xb  = X  + (size_t)b*I*C_;
  const float* Y1b = Y1 + (size_t)b*Jd*C_;
  const float* Y2b = Y2 + (size_t)b*Jd*C_;
  for (int c0 = 0; c0 < C_; c0 += 32){
    for (int e = threadIdx.x; e < 512; e += 256){
      int r = e >> 5, cc = e & 31;
      Xs[r][cc] = (i0+r < I) ? Xb[(size_t)(i0+r)*C_ + c0+cc] : 0.f;
    }
    for (int e = threadIdx.x; e < 2048; e += 256){
      int r = e >> 5, cc = e & 31;
      bool ok = (j0+r < Jd);
      Y1s[r][cc] = ok ? Y1b[(size_t)(j0+r)*C_ + c0+cc] : 0.f;
      Y2s[r][cc] = ok ? Y2b[(size_t)(j0+r)*C_ + c0+cc] : 0.f;
    }
    __syncthreads();
    for (int kk = 0; kk < 32; kk++){
      float y1 = Y1s[jl][kk], y2 = Y2s[jl][kk];
      #pragma unroll
      for (int k = 0; k < 4; k++){
        float x = Xs[ig*4+k][kk];
        acc1[k] += x*y1;
        acc2[k] += x*y2;
      }
    }
    __syncthreads();
  }
  #pragma unroll
  for (int k = 0; k < 4; k++){
    int i = i0 + ig*4 + k, j = j0 + jl;
    if (i < I && j < Jd){
      out1[((size_t)b*I + i)*Jd + j] = acc1[k];
      out2[((size_t)b*I + i)*Jd + j] = acc2[k];
    }
  }
}

// attA + fused lossA (round-17 proven config)
__global__ __launch_bounds__(128) void k_attA(const float* __restrict__ S1,
    const float* __restrict__ S2, const float* __restrict__ S3,
    const float* __restrict__ W4, const float* __restrict__ sc,
    const float* __restrict__ Mfix, float* __restrict__ Av, float* __restrict__ pa){
  __shared__ float red[128];
  int bq = blockIdx.x; int b = bq/MT_, q = bq % MT_;
  int j = threadIdx.x;
  float a1 = sc[2], be1 = sc[3];
  float v = -3.4e38f;
  if (j < HW){
    float s3 = 0.f;
    const float* S3b = S3 + (size_t)b*HW*HW + j;
    const float* w4 = W4 + (size_t)q*HW;
    for (int p = 0; p < HW; p++) s3 += w4[p]*S3b[(size_t)p*HW];
    size_t off = ((size_t)b*MT_ + q)*HW + j;
    v = (S1[off] + a1*S2[off] + be1*s3)*(1.f/SQC);
  }
  red[j] = v; __syncthreads();
  for (int o = 64; o > 0; o >>= 1){
    if (j < o) red[j] = fmaxf(red[j], red[j+o]);
    __syncthreads();
  }
  float m = red[0]; __syncthreads();
  float e = (j < HW) ? expf(v - m) : 0.f;
  red[j] = e; __syncthreads();
  for (int o = 64; o > 0; o >>= 1){
    if (j < o) red[j] += red[j+o];
    __syncthreads();
  }
  float av = (j < HW) ? e/red[0] : 0.f;
  if (j < HW) Av[((size_t)b*MT_ + q)*HW + j] = av;
  __syncthreads();
  float vm = (j < HW) ? Mfix[(size_t)bq*HW + j]*(1.f/SQC) : -3.4e38f;
  red[j] = vm; __syncthreads();
  for (int o = 64; o > 0; o >>= 1){
    if (j < o) red[j] = fmaxf(red[j], red[j+o]);
    __syncthreads();
  }
  float mm = red[0]; __syncthreads();
  float em = (j < HW) ? expf(vm - mm) : 0.f;
  red[j] = em; __syncthreads();
  for (int o = 64; o > 0; o >>= 1){
    if (j < o) red[j] += red[j+o];
    __syncthreads();
  }
  float fa = (j < HW) ? em/red[0] : 0.f;
  __syncthreads();
  float p[5] = { fabsf(av - fa), av, av*av, fa, fa*fa };
  for (int s = 0; s < 5; s++){
    red[j] = p[s]; __syncthreads();
    for (int o = 64; o > 0; o >>= 1){
      if (j < o) red[j] += red[j+o];
      __syncthreads();
    }
    if (j == 0) pa[bq*5 + s] = red[0];
    __syncthreads();
  }
}

// attB + fused lossB
__global__ __launch_bounds__(256) void k_attB(const float* __restrict__ S4a,
    const float* __restrict__ S4b, const float* __restrict__ S5,
    const float* __restrict__ W5, const float* __restrict__ sc,
    const float* __restrict__ Mfix, float* __restrict__ Bv, float* __restrict__ pb){
  __shared__ float red[8];
  int row = blockIdx.x*8 + (threadIdx.x >> 5);
  int lane = threadIdx.x & 31;
  int b = row/HW, i = row % HW;
  float a2 = sc[5], be2 = sc[6];
  float v = -3.4e38f;
  if (lane < MT_){
    float s5 = 0.f;
    const float* S5b = S5 + (size_t)b*MT_*MT_ + lane;
    const float* w5 = W5 + (size_t)i*MT_;
    #pragma unroll
    for (int p = 0; p < MT_; p++) s5 += w5[p]*S5b[p*MT_];
    size_t off = (size_t)row*MT_ + lane;
    v = (S4a[off] + a2*S4b[off] + be2*s5)*(1.f/SQC);
  }
  float m = v;
  for (int o = 16; o > 0; o >>= 1) m = fmaxf(m, __shfl_xor(m, o, 32));
  float e = (lane < MT_) ? expf(v - m) : 0.f;
  float s = e;
  for (int o = 16; o > 0; o >>= 1) s += __shfl_xor(s, o, 32);
  float bv = (lane < MT_) ? e/s : 0.f;
  if (lane < MT_) Bv[(size_t)row*MT_ + lane] = bv;
  float vm = (lane < MT_) ? Mfix[((size_t)b*MT_ + lane)*HW + i]*(1.f/SQC) : -3.4e38f;
  float mm = vm;
  for (int o = 16; o > 0; o >>= 1) mm = fmaxf(mm, __shfl_xor(mm, o, 32));
  float em = (lane < MT_) ? expf(vm - mm) : 0.f;
  float sm = em;
  for (int o = 16; o > 0; o >>= 1) sm += __shfl_xor(sm, o, 32);
  float fb = (lane < MT_) ? em/sm : 0.f;
  float p[5] = { fabsf(bv - fb), bv, bv*bv, fb, fb*fb };
  for (int s5 = 0; s5 < 5; s5++){
    float x = p[s5];
    for (int o = 16; o > 0; o >>= 1) x += __shfl_xor(x, o, 32);
    if (lane == 0) red[threadIdx.x >> 5] = x;
    __syncthreads();
    if (threadIdx.x == 0){
      float t = 0.f;
      for (int g = 0; g < 8; g++) t += red[g];
      pb[blockIdx.x*5 + s5] = t;
    }
    __syncthreads();
  }
}

__global__ __launch_bounds__(256) void k_nl(const float* __restrict__ Av,
    const float* __restrict__ Pt2i, const float* __restrict__ Vf,
    const float* __restrict__ sc, float* __restrict__ NL){
  __shared__ float sA[MT_][HW];
  int b = blockIdx.y; int m = blockIdx.x*256 + threadIdx.x;
  float g1 = sc[4];
  for (int e = threadIdx.x; e < MT_*HW; e += 256)
    sA[e/HW][e%HW] = Av[(size_t)b*MT_*HW + e] + g1*Pt2i[(size_t)b*MT_*HW + e];
  __syncthreads();
  float acc[MT_];
  #pragma unroll
  for (int q = 0; q < MT_; q++) acc[q] = 0.f;
  for (int k = 0; k < HW; k++){
    float v = Vf[((size_t)b*HW + k)*C_ + m];
    #pragma unroll
    for (int q = 0; q < MT_; q++) acc[q] += sA[q][k]*v;
  }
  #pragma unroll
  for (int q = 0; q < MT_; q++) NL[((size_t)b*MT_ + q)*C_ + m] = acc[q];
}

__global__ __launch_bounds__(256) void k_nv(const float* __restrict__ Bv,
    const float* __restrict__ Pi2t, const float* __restrict__ Vt,
    const float* __restrict__ sc, short* __restrict__ NVb){
  __shared__ float sB[HW][MT_];
  int b = blockIdx.y; int m = blockIdx.x*256 + threadIdx.x;
  float g2 = sc[7];
  for (int e = threadIdx.x; e < HW*MT_; e += 256)
    sB[e/MT_][e%MT_] = Bv[(size_t)b*HW*MT_ + e] + g2*Pi2t[(size_t)b*HW*MT_ + e];
  __syncthreads();
  float vT[MT_];
  #pragma unroll
  for (int j = 0; j < MT_; j++) vT[j] = Vt[((size_t)b*MT_ + j)*C_ + m];
  for (int i = 0; i < HW; i++){
    float a = 0.f;
    #pragma unroll
    for (int j = 0; j < MT_; j++) a += sB[i][j]*vT[j];
    NVb[((size_t)b*HW + i)*C_ + m] = f2bf(a);
  }
}

__global__ __launch_bounds__(256) void k_loss_final(const float* __restrict__ pa,
    const float* __restrict__ pb, float* __restrict__ outloss){
  __shared__ float red[256];
  float s[5] = {0,0,0,0,0}, t[5] = {0,0,0,0,0};
  for (int r = threadIdx.x; r < 1280; r += 256)
    for (int k = 0; k < 5; k++) s[k] += pa[r*5 + k];
  for (int r = threadIdx.x; r < 800; r += 256)
    for (int k = 0; k < 5; k++) t[k] += pb[r*5 + k];
  float res[10];
  for (int k = 0; k < 5; k++){
    red[threadIdx.x] = s[k]; __syncthreads();
    for (int o = 128; o > 0; o >>= 1){
      if ((int)threadIdx.x < o) red[threadIdx.x] += red[threadIdx.x+o];
      __syncthreads();
    }
    res[k] = red[0]; __syncthreads();
  }
  for (int k = 0; k < 5; k++){
    red[threadIdx.x] = t[k]; __syncthreads();
    for (int o = 128; o > 0; o >>= 1){
      if ((int)threadIdx.x < o) red[threadIdx.x] += red[threadIdx.x+o];
      __syncthreads();
    }
    res[5+k] = red[0]; __syncthreads();
  }
  if (threadIdx.x == 0){
    const float n = 128000.f;
    float l1 = res[0]/n + res[5]/n;
    float varAv = (res[2] - res[1]*res[1]/n)/(n - 1.f);
    float varfA = (res[4] - res[3]*res[3]/n)/(n - 1.f);
    float varBv = (res[7] - res[6]*res[6]/n)/(n - 1.f);
    float varfB = (res[9] - res[8]*res[8]/n)/(n - 1.f);
    float l2 = -fabsf(varAv - varfA) - fabsf(varBv - varfB);
    outloss[0] = (l1 + 100.f*l2)*1000.f;
  }
}

// ---------------- launcher ----------------
extern "C" void kernel_launch(void* const* d_in, const int* in_sizes, int n_in,
                              void* d_out, int out_size, void* d_ws, size_t ws_size,
                              hipStream_t stream){
  const float* ir     = (const float*)d_in[0];
  const float* vis    = (const float*)d_in[1];
  const float* lan    = (const float*)d_in[2];
  const float* vis_w  = (const float*)d_in[3];
  const float* vis_g  = (const float*)d_in[5];
  const float* vis_be = (const float*)d_in[6];
  const float* ir_w   = (const float*)d_in[7];
  const float* ir_g   = (const float*)d_in[9];
  const float* ir_be  = (const float*)d_in[10];
  const float* t_w    = (const float*)d_in[11];
  const float* t_b    = (const float*)d_in[12];
  const float* vout_w = (const float*)d_in[13];
  const float* vout_b = (const float*)d_in[14];
  const float* tout_w = (const float*)d_in[15];
  const float* tout_b = (const float*)d_in[16];
  const float* W1     = (const float*)d_in[17];
  const float* b1     = (const float*)d_in[18];
  const float* W2     = (const float*)d_in[19];
  const float* b2     = (const float*)d_in[20];
  const float* W4     = (const float*)d_in[21];
  const float* W5     = (const float*)d_in[22];
  const float* ml_w   = (const float*)d_in[23];
  const float* ml_b   = (const float*)d_in[24];
  const float* ml2_w  = (const float*)d_in[25];
  const float* ml2_b  = (const float*)d_in[26];
  const float* sc     = (const float*)d_in[27];

  float* ws = (float*)d_ws;
  float* J     = ws + F_J;
  float* Dm    = ws + F_D;
  float* sqb   = ws + F_SQ;
  int*   knn   = (int*)(ws + F_KNN);
  float* Mv    = ws + F_MV;
  float* Mt    = ws + F_MT;
  float* Mfix  = ws + F_MFIX;
  float* QKVf  = ws + F_QKVF;
  float* QKVt  = ws + F_QKVT;
  float* feat  = ws + F_FEAT;
  float* lanML = ws + F_LANML;
  float* T2b   = ws + F_T2;
  float* Mi2tL = ws + F_MI2TL;
  float* S1    = ws + F_S1;
  float* S2    = ws + F_S2;
  float* S4a   = ws + F_S4A;
  float* S4b   = ws + F_S4B;
  float* S5    = ws + F_S5;
  float* Av    = ws + F_AV;
  float* Bv    = ws + F_BV;
  float* NL    = ws + F_NL;
  float* alpha = ws + F_AL;
  float* bet   = ws + F_BE;
  float* hs    = ws + F_HS;
  unsigned* hist = (unsigned*)(ws + F_HIST);
  float* pa    = ws + F_PA;
  float* pb    = ws + F_PB;
  // overlays
  float* MlT2I = ws + F_J;
  float* S3    = ws + F_D;
  float* Pi2t  = ws + F_MV;
  float* Pt2i  = ws + F_MV + 128000;
  float* Ppre  = ws + F_MV + 256000;
  // bf16 overlays
  short* XtV    = (short*)(ws + F_J);
  short* XtI    = (short*)(ws + F_J + 3300000);
  short* WVb    = (short*)(ws + F_J + 6600000);
  short* WIb    = (short*)(ws + F_J + 8200000);
  short* NVb    = (short*)(ws + F_J + 6553600);
  short* Wob16  = (short*)(ws + F_J + 9830400);
  short* lanTb  = (short*)(ws + F_J + 10360000);
  short* Wtb    = (short*)(ws + F_D);
  short* tout16 = (short*)(ws + F_D + 1000000);
  short* ml2w16 = (short*)(ws + F_D + 1530000);

  float* out_vis  = (float*)d_out;
  float* out_lan  = out_vis + (size_t)B_*C_*HW;
  float* out_loss = out_lan + (size_t)B_*MT_*C_;

  float* Qf = QKVf;
  float* Kf = QKVf + (size_t)B_*HW*C_;
  float* Vf = QKVf + (size_t)2*B_*HW*C_;
  float* Qt = QKVt;
  float* Kt = QKVt + (size_t)B_*MT_*C_;
  float* Vt = QKVt + (size_t)2*B_*MT_*C_;

  // ---- geodesic 1 (vis ++ ir) ----
  k_pack_j1<<<dim3(32,7,B_),256,0,stream>>>(vis, ir, J);
  k_rowsq<<<B_*P1,64,0,stream>>>(J, sqb, P1);
  k_gram_dist<<<dim3(4,4,B_),256,0,stream>>>(J, sqb, Dm, P1);
  k_knn<P1><<<B_*P1,64,0,stream>>>(Dm, knn);
  k_fwx<P1,1024,10,4,0,100,100,100><<<B_,1024,0,stream>>>(Dm, knn, Mv);
  k_med_init<<<1,64,0,stream>>>(hs);
  for (int it = 0; it < 2; it++){
    hipMemsetAsync(hist, 0, 1025*sizeof(unsigned), stream);
    k_med_hist<<<256,256,0,stream>>>(Mv, B_*HW*HW, hs, hist);
    k_med_select<<<1,64,0,stream>>>(hs, hist, B_*HW*HW/2);
  }
  k_mgap<<<B_,256,0,stream>>>(Mv, W1, b1, sc, hs, alpha, bet);

  // ---- projections (bf16 MFMA paths) ----
  k_castw<<<(3*C_*C_/4+255)/256,256,0,stream>>>(vis_w, ir_w, WVb, WIb);
  k_cast<<<(C_*C_/4+255)/256,256,0,stream>>>(vout_w, Wob16, C_*C_);
  k_cast2<<<((4*C_*C_)/4+255)/256,256,0,stream>>>(t_w, ml_w, Wtb,
                                                  Wtb + (size_t)3*C_*C_,
                                                  3*C_*C_, C_*C_);
  k_xt2<<<dim3(32,4,B_),256,0,stream>>>(vis, ir, alpha, bet, XtV, XtI, feat);
  k_lanT<<<dim3(32,B_),256,0,stream>>>(lan, lanTb);
  k_convqkv_mfma<<<dim3(8,3,B_),256,0,stream>>>(XtV, XtI, WVb, WIb,
                                                vis_g, vis_be, ir_g, ir_be,
                                                alpha, bet, QKVf);
  k_textproj_mfma<<<dim3(8,12,4),256,0,stream>>>(lanTb, Wtb, t_b, QKVt, lanML);
  k_cast2<<<((2*C_*C_)/4+255)/256,256,0,stream>>>(tout_w, ml2_w, tout16, ml2w16,
                                                  C_*C_, C_*C_);

  // ---- geodesic 2 (feat ++ lan) ----
  k_pack_j2<<<(B_*P2*C_+255)/256,256,0,stream>>>(feat, lan, J);
  k_rowsq<<<B_*P2,64,0,stream>>>(J, sqb, P2);
  k_gram_dist<<<dim3(2,2,B_),256,0,stream>>>(J, sqb, Dm, P2);
  k_knn<P2><<<B_*P2,64,0,stream>>>(Dm, knn);
  k_fwx<P2,960,4,4,100,0,MT_,100><<<B_,960,0,stream>>>(Dm, knn, Mt);
  k_med_init<<<1,64,0,stream>>>(hs+2);
  for (int it = 0; it < 2; it++){
    hipMemsetAsync(hist, 0, 1025*sizeof(unsigned), stream);
    k_med_hist<<<256,256,0,stream>>>(Mt, B_*MT_*HW, hs+2, hist);
    k_med_select<<<1,64,0,stream>>>(hs+2, hist, B_*MT_*HW/2);
  }
  k_mfixppre<<<(B_*MT_*HW+255)/256,256,0,stream>>>(Mt, hs+2, W2, b2, sc, Mfix, Ppre);
  k_sm20<<<(B_*HW+7)/8,256,0,stream>>>(Ppre, Pi2t);
  k_smT<<<B_*MT_,128,0,stream>>>(Ppre, Pt2i);

  // ---- manifold-learned matrices ----
  k_mlearn_t2i<<<dim3(4,B_),256,0,stream>>>(Pi2t, lanML, ml_b, MlT2I);
  k_t2<<<dim3(4,B_),256,0,stream>>>(Pt2i, feat, T2b);
  k_tokproj_mfma<<<dim3(8,12),256,0,stream>>>(T2b, ml2w16, ml2_b, Mi2tL);

  // ---- attention scores (+ fused loss partials) ----
  k_abt2<<<dim3(2,2,B_),256,0,stream>>>(Qt, Kf, MlT2I, S1, S2, MT_, HW);
  k_s3_mfma<<<dim3(2,B_),256,0,stream>>>(MlT2I, Kf, S3);
  k_abt2<<<dim3(7,1,B_),256,0,stream>>>(Qf, Kt, Mi2tL, S4a, S4b, HW, MT_);
  k_abt<<<dim3(2,1,B_),256,0,stream>>>(Mi2tL, Kt, S5, MT_, MT_);
  k_attA<<<B_*MT_,128,0,stream>>>(S1, S2, S3, W4, sc, Mfix, Av, pa);
  k_attB<<<B_*HW/8,256,0,stream>>>(S4a, S4b, S5, W5, sc, Mfix, Bv, pb);

  // ---- outputs ----
  k_nl<<<dim3(4,B_),256,0,stream>>>(Av, Pt2i, Vf, sc, NL);
  k_nv<<<dim3(4,B_),256,0,stream>>>(Bv, Pi2t, Vt, sc, NVb);
  k_tokproj_mfma<<<dim3(8,12),256,0,stream>>>(NL, tout16, tout_b, out_lan);
  k_convout_mfma<<<dim3(8,B_),256,0,stream>>>(NVb, Wob16, vout_b, out_vis);

  // ---- loss ----
  k_loss_final<<<1,256,0,stream>>>(pa, pb, out_loss);
}